// Round 1
// baseline (616.315 us; speedup 1.0000x reference)
//
#include <hip/hip_runtime.h>
#include <math.h>

#define Bz 8
#define NQ 4096
#define NKV 4096
#define Cc 256
#define KNN 16
#define Hh 32
#define EPSf 1e-5f
#define SLOPEf 0.2f
#define NSLICE 4
#define SLICE (NKV / NSLICE) /* 1024 */

// ---- workspace layout (bytes) ----
#define OFF_W1AS 0u                       // 32*256 f32 (alpha1-folded w1a)
#define OFF_W1DS (OFF_W1AS + 32768u)      // 32*256 f32 (alpha1-folded (w1b-w1a))
#define OFF_W2T  (OFF_W1DS + 32768u)      // 32*256 f32 w2t[h][c] = alpha2[c]*w2[c][h]
#define OFF_C1   (OFF_W2T + 32768u)       // 32 f32: b1 - alpha1*m1
#define OFF_B2F  (OFF_C1 + 1024u)         // 256 f32: b2 - alpha2*m2
#define OFF_KVP  (OFF_B2F + 2048u)        // 8*4096 float4 packed kv xyz
#define OFF_QP   (OFF_KVP + 524288u)      // 8*4096 float4 packed q xyz
#define OFF_KVS  (OFF_QP + 524288u)       // 8*4096*32 f32
#define OFF_QADD (OFF_KVS + 4194304u)     // 8*4096*32 f32
#define OFF_PD   (OFF_QADD + 4194304u)    // 8*4096*64 f32 partial top-16 dists (4 slices)
#define OFF_PI   (OFF_PD + 8388608u)      // 8*4096*64 i32 partial top-16 indices
#define OFF_X    (OFF_PI + 8388608u)      // 8*4096*32 f32 pooled hidden
// total ~30.5 MB

__device__ __forceinline__ float leaky(float x) { return fmaxf(x, SLOPEf * x); }

// ---------------- kernel 0: fold weights + pack xyz as float4 ----------------
__global__ __launch_bounds__(256) void k_prep(
    const float* __restrict__ qxyz, const float* __restrict__ kxyz,
    const float* __restrict__ w1, const float* __restrict__ g1,
    const float* __restrict__ b1, const float* __restrict__ m1,
    const float* __restrict__ v1, const float* __restrict__ w2,
    const float* __restrict__ g2, const float* __restrict__ b2,
    const float* __restrict__ m2, const float* __restrict__ v2,
    char* __restrict__ ws) {
  int t = threadIdx.x;
  if (blockIdx.x == 0) {
    __shared__ float a1[Hh], a2c[Cc];
    if (t < Hh) a1[t] = g1[t] / sqrtf(v1[t] + EPSf);
    if (t < Cc) a2c[t] = g2[t] / sqrtf(v2[t] + EPSf);
    __syncthreads();
    float* w1as = (float*)(ws + OFF_W1AS);
    float* w1ds = (float*)(ws + OFF_W1DS);
    float* w2t  = (float*)(ws + OFF_W2T);
    float* c1   = (float*)(ws + OFF_C1);
    float* b2f  = (float*)(ws + OFF_B2F);
    for (int i = t; i < Hh * Cc; i += 256) {
      int h = i >> 8, c = i & 255;
      float wa = w1[h * 2 * Cc + c];
      float wb = w1[h * 2 * Cc + Cc + c];
      w1as[i] = a1[h] * wa;
      w1ds[i] = a1[h] * (wb - wa);
      w2t[i] = a2c[c] * w2[c * Hh + h];   // i = h*256 + c
    }
    if (t < Hh) c1[t] = b1[t] - a1[t] * m1[t];
    if (t < Cc) b2f[t] = b2[t] - a2c[t] * m2[t];
  } else {
    // pack xyz -> float4 (65536 points over 64 blocks)
    float4* kvp = (float4*)(ws + OFF_KVP);
    float4* qp  = (float4*)(ws + OFF_QP);
    for (int i = 0; i < 4; ++i) {
      int g = (blockIdx.x - 1) * 1024 + i * 256 + t;  // 0..65535
      const float* src;
      float4* dst;
      if (g < Bz * NKV) { src = kxyz + (size_t)g * 3; dst = kvp + g; }
      else { int g2i = g - Bz * NKV; src = qxyz + (size_t)g2i * 3; dst = qp + g2i; }
      float4 v; v.x = src[0]; v.y = src[1]; v.z = src[2]; v.w = 0.f;
      *dst = v;
    }
  }
}

// ------------- kernel 1: kvs = (a1*w1a)·kv_feat ; qadd = (a1*w1d)·q_feat + c1 -------------
__global__ __launch_bounds__(256) void k_feat(
    const float* __restrict__ kvf, const float* __restrict__ qf,
    const char* __restrict__ ws_c, char* __restrict__ ws_o) {
  __shared__ __align__(16) float fs[64][68];
  __shared__ __align__(16) float wsh[32][68];
  int t = threadIdx.x;
  int hh = t & 15, rr = t >> 4;
  int b = blockIdx.y, m0 = blockIdx.x * 64, mode = blockIdx.z;
  const float* in = mode ? qf : kvf;
  const float* w = (const float*)(ws_c + (mode ? OFF_W1DS : OFF_W1AS));
  const float* c1 = (const float*)(ws_c + OFF_C1);
  float* out = (float*)(ws_o + (mode ? OFF_QADD : OFF_KVS));
  const float* inb = in + ((size_t)b * NKV + m0) * Cc;
  float acc[2][4] = {{0.f, 0.f, 0.f, 0.f}, {0.f, 0.f, 0.f, 0.f}};
  for (int cc = 0; cc < 4; ++cc) {
    __syncthreads();
#pragma unroll
    for (int i = 0; i < 4; ++i) {  // stage 64x64 feat tile
      int l = i * 256 + t, row = l >> 4, c4 = l & 15;
      *(float4*)&fs[row][c4 * 4] = *(const float4*)(inb + (size_t)row * Cc + cc * 64 + c4 * 4);
    }
#pragma unroll
    for (int i = 0; i < 2; ++i) {  // stage 32x64 weight tile
      int l = i * 256 + t, row = l >> 4, c4 = l & 15;
      *(float4*)&wsh[row][c4 * 4] = *(const float4*)(w + (size_t)row * Cc + cc * 64 + c4 * 4);
    }
    __syncthreads();
#pragma unroll
    for (int c4 = 0; c4 < 16; ++c4) {
      float4 w0 = *(float4*)&wsh[hh][c4 * 4];
      float4 w1v = *(float4*)&wsh[hh + 16][c4 * 4];
#pragma unroll
      for (int j = 0; j < 4; ++j) {
        float4 f = *(float4*)&fs[rr + j * 16][c4 * 4];
        acc[0][j] = fmaf(w0.x, f.x, fmaf(w0.y, f.y, fmaf(w0.z, f.z, fmaf(w0.w, f.w, acc[0][j]))));
        acc[1][j] = fmaf(w1v.x, f.x, fmaf(w1v.y, f.y, fmaf(w1v.z, f.z, fmaf(w1v.w, f.w, acc[1][j]))));
      }
    }
  }
  float add0 = mode ? c1[hh] : 0.f;
  float add1 = mode ? c1[hh + 16] : 0.f;
  float* ob = out + ((size_t)b * NKV + m0) * Hh;
#pragma unroll
  for (int j = 0; j < 4; ++j) {
    ob[(rr + j * 16) * Hh + hh] = acc[0][j] + add0;
    ob[(rr + j * 16) * Hh + hh + 16] = acc[1][j] + add1;
  }
}

// ------------- kernel 2: per-slice top-16 selection (one query per thread) -------------
__global__ __launch_bounds__(256) void k_select(
    const char* __restrict__ ws_c, float* __restrict__ pd, int* __restrict__ pi) {
  __shared__ float4 lk[SLICE];  // 16 KB slice of packed kv xyz
  int t = threadIdx.x;
  int qt = blockIdx.x, s = blockIdx.y, b = blockIdx.z;
  const float4* kvp = (const float4*)(ws_c + OFF_KVP);
  const float4* qp = (const float4*)(ws_c + OFF_QP);
  const float4* src = kvp + (size_t)b * NKV + s * SLICE;
#pragma unroll
  for (int i = 0; i < SLICE / 256; ++i) lk[i * 256 + t] = src[i * 256 + t];
  int q = qt * 256 + t;
  float4 qv = qp[(size_t)b * NQ + q];
  __syncthreads();
  float bd[KNN];
  int bi[KNN];
#pragma unroll
  for (int j = 0; j < KNN; ++j) { bd[j] = 3.4e38f; bi[j] = 0; }
  for (int mm = 0; mm < SLICE; ++mm) {
    float4 kv = lk[mm];
    float dx = qv.x - kv.x, dy = qv.y - kv.y, dz = qv.z - kv.z;
    float d = fmaf(dz, dz, fmaf(dy, dy, dx * dx));
    if (d < bd[KNN - 1]) {  // divergent, but body only runs ~2% of lane-steps
      float v = d;
      int vi = s * SLICE + mm;
#pragma unroll
      for (int j = 0; j < KNN; ++j) {
        bool clt = v < bd[j];
        float tv = bd[j]; int ti = bi[j];
        bd[j] = clt ? v : tv;  bi[j] = clt ? vi : ti;
        v = clt ? tv : v;      vi = clt ? ti : vi;
      }
    }
  }
  size_t base = ((size_t)b * NQ + q) * 64 + (size_t)s * KNN;
#pragma unroll
  for (int j = 0; j < KNN; ++j) { pd[base + j] = bd[j]; pi[base + j] = bi[j]; }
}

// ------------- kernel 3: merge 4 slices, gather kvs, max-pool, hidden x -------------
__global__ __launch_bounds__(256) void k_merge(
    const float* __restrict__ pd, const int* __restrict__ pi,
    const char* __restrict__ ws_c, float* __restrict__ xout) {
  int t = threadIdx.x;
  int q = blockIdx.x * 256 + t, b = blockIdx.y;
  const float* kvs = (const float*)(ws_c + OFF_KVS);
  const float* qadd = (const float*)(ws_c + OFF_QADD);
  size_t base = ((size_t)b * NQ + q) * 64;
  float bd[KNN];
  int bi[KNN];
#pragma unroll
  for (int j = 0; j < KNN; ++j) { bd[j] = pd[base + j]; bi[j] = pi[base + j]; }
  for (int sj = KNN; sj < 4 * KNN; ++sj) {
    float d = pd[base + sj];
    if (d < bd[KNN - 1]) {
      float v = d;
      int vi = pi[base + sj];
#pragma unroll
      for (int j = 0; j < KNN; ++j) {
        bool clt = v < bd[j];
        float tv = bd[j]; int ti = bi[j];
        bd[j] = clt ? v : tv;  bi[j] = clt ? vi : ti;
        v = clt ? tv : v;      vi = clt ? ti : vi;
      }
    }
  }
  float4 sacc[8];
#pragma unroll
  for (int n = 0; n < KNN; ++n) {
    const float4* row = (const float4*)(kvs + ((size_t)b * NKV + bi[n]) * Hh);
#pragma unroll
    for (int j = 0; j < 8; ++j) {
      float4 vv = row[j];
      if (n == 0) sacc[j] = vv;
      else {
        sacc[j].x = fmaxf(sacc[j].x, vv.x); sacc[j].y = fmaxf(sacc[j].y, vv.y);
        sacc[j].z = fmaxf(sacc[j].z, vv.z); sacc[j].w = fmaxf(sacc[j].w, vv.w);
      }
    }
  }
  const float4* qa = (const float4*)(qadd + ((size_t)b * NQ + q) * Hh);
  float4* xo = (float4*)(xout + ((size_t)b * NQ + q) * Hh);
#pragma unroll
  for (int j = 0; j < 8; ++j) {
    float4 a = qa[j];
    float4 r;
    r.x = leaky(sacc[j].x + a.x); r.y = leaky(sacc[j].y + a.y);
    r.z = leaky(sacc[j].z + a.z); r.w = leaky(sacc[j].w + a.w);
    xo[j] = r;
  }
}

// ------------- kernel 4: y = leaky(w2t · x + b2f) -------------
__global__ __launch_bounds__(256) void k_out(
    const float* __restrict__ x, const char* __restrict__ ws_c,
    float* __restrict__ out) {
  int t = threadIdx.x;
  int ql = t & 63, cb = t >> 6;  // cb is wave-uniform -> w2t loads become scalar
  int b = blockIdx.y, q = blockIdx.x * 64 + ql;
  const float* w2t = (const float*)(ws_c + OFF_W2T);
  const float* b2f = (const float*)(ws_c + OFF_B2F);
  const float4* xr = (const float4*)(x + ((size_t)b * NQ + q) * Hh);
  float xv[Hh];
#pragma unroll
  for (int j = 0; j < 8; ++j) {
    float4 v = xr[j];
    xv[4 * j] = v.x; xv[4 * j + 1] = v.y; xv[4 * j + 2] = v.z; xv[4 * j + 3] = v.w;
  }
  float4 acc[16];
#pragma unroll
  for (int c4 = 0; c4 < 16; ++c4) acc[c4] = make_float4(0.f, 0.f, 0.f, 0.f);
#pragma unroll
  for (int h = 0; h < Hh; ++h) {
    float xh = xv[h];
    const float4* wrow = (const float4*)(w2t + (size_t)h * Cc + cb * 64);
#pragma unroll
    for (int c4 = 0; c4 < 16; ++c4) {
      float4 w = wrow[c4];
      acc[c4].x = fmaf(xh, w.x, acc[c4].x);
      acc[c4].y = fmaf(xh, w.y, acc[c4].y);
      acc[c4].z = fmaf(xh, w.z, acc[c4].z);
      acc[c4].w = fmaf(xh, w.w, acc[c4].w);
    }
  }
  float* o = out + ((size_t)b * NQ + q) * Cc + cb * 64;
  const float4* bb = (const float4*)(b2f + cb * 64);
#pragma unroll
  for (int c4 = 0; c4 < 16; ++c4) {
    float4 bv = bb[c4];
    float4 r;
    r.x = leaky(acc[c4].x + bv.x); r.y = leaky(acc[c4].y + bv.y);
    r.z = leaky(acc[c4].z + bv.z); r.w = leaky(acc[c4].w + bv.w);
    *(float4*)(o + c4 * 4) = r;
  }
}

extern "C" void kernel_launch(void* const* d_in, const int* in_sizes, int n_in,
                              void* d_out, int out_size, void* d_ws, size_t ws_size,
                              hipStream_t stream) {
  const float* qf   = (const float*)d_in[0];
  const float* qxyz = (const float*)d_in[1];
  const float* kvf  = (const float*)d_in[2];
  const float* kxyz = (const float*)d_in[3];
  const float* w1 = (const float*)d_in[4];
  const float* g1 = (const float*)d_in[5];
  const float* b1 = (const float*)d_in[6];
  const float* m1 = (const float*)d_in[7];
  const float* v1 = (const float*)d_in[8];
  const float* w2 = (const float*)d_in[9];
  const float* g2 = (const float*)d_in[10];
  const float* b2 = (const float*)d_in[11];
  const float* m2 = (const float*)d_in[12];
  const float* v2 = (const float*)d_in[13];
  char* ws = (char*)d_ws;
  float* pd = (float*)(ws + OFF_PD);
  int* pi = (int*)(ws + OFF_PI);
  float* xbuf = (float*)(ws + OFF_X);

  k_prep<<<65, 256, 0, stream>>>(qxyz, kxyz, w1, g1, b1, m1, v1, w2, g2, b2, m2, v2, ws);
  k_feat<<<dim3(64, Bz, 2), 256, 0, stream>>>(kvf, qf, ws, ws);
  k_select<<<dim3(NQ / 256, NSLICE, Bz), 256, 0, stream>>>(ws, pd, pi);
  k_merge<<<dim3(NQ / 256, Bz), 256, 0, stream>>>(pd, pi, ws, xbuf);
  k_out<<<dim3(NQ / 64, Bz), 256, 0, stream>>>(xbuf, ws, (float*)d_out);
}

// Round 2
// 589.013 us; speedup vs baseline: 1.0464x; 1.0464x over previous
//
#include <hip/hip_runtime.h>
#include <math.h>

#define Bz 8
#define NQ 4096
#define NKV 4096
#define Cc 256
#define KNN 16
#define Hh 32
#define EPSf 1e-5f
#define SLOPEf 0.2f
#define NSL 8
#define SL 512 /* NKV / NSL */

// ---- workspace layout (bytes) ----
#define OFF_W1AS 0u                       // 32*256 f32 (alpha1-folded w1a)
#define OFF_W1DS (OFF_W1AS + 32768u)      // 32*256 f32 (alpha1-folded (w1b-w1a))
#define OFF_W2T  (OFF_W1DS + 32768u)      // 32*256 f32 w2t[h][c] = alpha2[c]*w2[c][h]
#define OFF_C1   (OFF_W2T + 32768u)       // 32 f32: b1 - alpha1*m1
#define OFF_B2F  (OFF_C1 + 1024u)         // 256 f32: b2 - alpha2*m2
#define OFF_KVP  (OFF_B2F + 2048u)        // 8*4096 float4 packed kv xyz (w = |k|^2)
#define OFF_QP   (OFF_KVP + 524288u)      // 8*4096 float4 packed q xyz
#define OFF_KVS  (OFF_QP + 524288u)       // 8*4096*32 f32
#define OFF_QADD (OFF_KVS + 4194304u)     // 8*4096*32 f32
#define OFF_PD   (OFF_QADD + 4194304u)    // 8*4096*8*16 f32 per-slice sorted top-16 dists (16 MB)
#define OFF_X    (OFF_PD + 16777216u)     // 8*4096*32 f32 pooled hidden
// total ~30.5 MB (same as round 1)

__device__ __forceinline__ float leaky(float x) { return fmaxf(x, SLOPEf * x); }

// deterministic rank key: s = |k|^2 - 2 q.k   (must be bit-identical in selA/selB)
__device__ __forceinline__ float distkey(float qx2, float qy2, float qz2, float4 kv) {
  return fmaf(qx2, kv.x, fmaf(qy2, kv.y, fmaf(qz2, kv.z, kv.w)));
}

// ---------------- kernel 0: fold weights + pack xyz as float4 ----------------
__global__ __launch_bounds__(256) void k_prep(
    const float* __restrict__ qxyz, const float* __restrict__ kxyz,
    const float* __restrict__ w1, const float* __restrict__ g1,
    const float* __restrict__ b1, const float* __restrict__ m1,
    const float* __restrict__ v1, const float* __restrict__ w2,
    const float* __restrict__ g2, const float* __restrict__ b2,
    const float* __restrict__ m2, const float* __restrict__ v2,
    char* __restrict__ ws) {
  int t = threadIdx.x;
  if (blockIdx.x == 0) {
    __shared__ float a1[Hh], a2c[Cc];
    if (t < Hh) a1[t] = g1[t] / sqrtf(v1[t] + EPSf);
    if (t < Cc) a2c[t] = g2[t] / sqrtf(v2[t] + EPSf);
    __syncthreads();
    float* w1as = (float*)(ws + OFF_W1AS);
    float* w1ds = (float*)(ws + OFF_W1DS);
    float* w2t  = (float*)(ws + OFF_W2T);
    float* c1   = (float*)(ws + OFF_C1);
    float* b2f  = (float*)(ws + OFF_B2F);
    for (int i = t; i < Hh * Cc; i += 256) {
      int h = i >> 8, c = i & 255;
      float wa = w1[h * 2 * Cc + c];
      float wb = w1[h * 2 * Cc + Cc + c];
      w1as[i] = a1[h] * wa;
      w1ds[i] = a1[h] * (wb - wa);
      w2t[i] = a2c[c] * w2[c * Hh + h];   // i = h*256 + c
    }
    if (t < Hh) c1[t] = b1[t] - a1[t] * m1[t];
    if (t < Cc) b2f[t] = b2[t] - a2c[t] * m2[t];
  } else {
    // pack xyz -> float4 (65536 points over 64 blocks); kv gets |k|^2 in .w
    float4* kvp = (float4*)(ws + OFF_KVP);
    float4* qp  = (float4*)(ws + OFF_QP);
    for (int i = 0; i < 4; ++i) {
      int g = (blockIdx.x - 1) * 1024 + i * 256 + t;  // 0..65535
      if (g < Bz * NKV) {
        const float* src = kxyz + (size_t)g * 3;
        float4 v; v.x = src[0]; v.y = src[1]; v.z = src[2];
        v.w = fmaf(v.x, v.x, fmaf(v.y, v.y, v.z * v.z));
        kvp[g] = v;
      } else {
        int g2i = g - Bz * NKV;
        const float* src = qxyz + (size_t)g2i * 3;
        float4 v; v.x = src[0]; v.y = src[1]; v.z = src[2]; v.w = 0.f;
        qp[g2i] = v;
      }
    }
  }
}

// ------------- kernel 1: kvs = (a1*w1a)·kv_feat ; qadd = (a1*w1d)·q_feat + c1 -------------
__global__ __launch_bounds__(256) void k_feat(
    const float* __restrict__ kvf, const float* __restrict__ qf,
    const char* __restrict__ ws_c, char* __restrict__ ws_o) {
  __shared__ __align__(16) float fs[64][68];
  __shared__ __align__(16) float wsh[32][68];
  int t = threadIdx.x;
  int hh = t & 15, rr = t >> 4;
  int b = blockIdx.y, m0 = blockIdx.x * 64, mode = blockIdx.z;
  const float* in = mode ? qf : kvf;
  const float* w = (const float*)(ws_c + (mode ? OFF_W1DS : OFF_W1AS));
  const float* c1 = (const float*)(ws_c + OFF_C1);
  float* out = (float*)(ws_o + (mode ? OFF_QADD : OFF_KVS));
  const float* inb = in + ((size_t)b * NKV + m0) * Cc;
  float acc[2][4] = {{0.f, 0.f, 0.f, 0.f}, {0.f, 0.f, 0.f, 0.f}};
  for (int cc = 0; cc < 4; ++cc) {
    __syncthreads();
#pragma unroll
    for (int i = 0; i < 4; ++i) {  // stage 64x64 feat tile
      int l = i * 256 + t, row = l >> 4, c4 = l & 15;
      *(float4*)&fs[row][c4 * 4] = *(const float4*)(inb + (size_t)row * Cc + cc * 64 + c4 * 4);
    }
#pragma unroll
    for (int i = 0; i < 2; ++i) {  // stage 32x64 weight tile
      int l = i * 256 + t, row = l >> 4, c4 = l & 15;
      *(float4*)&wsh[row][c4 * 4] = *(const float4*)(w + (size_t)row * Cc + cc * 64 + c4 * 4);
    }
    __syncthreads();
#pragma unroll
    for (int c4 = 0; c4 < 16; ++c4) {
      float4 w0 = *(float4*)&wsh[hh][c4 * 4];
      float4 w1v = *(float4*)&wsh[hh + 16][c4 * 4];
#pragma unroll
      for (int j = 0; j < 4; ++j) {
        float4 f = *(float4*)&fs[rr + j * 16][c4 * 4];
        acc[0][j] = fmaf(w0.x, f.x, fmaf(w0.y, f.y, fmaf(w0.z, f.z, fmaf(w0.w, f.w, acc[0][j]))));
        acc[1][j] = fmaf(w1v.x, f.x, fmaf(w1v.y, f.y, fmaf(w1v.z, f.z, fmaf(w1v.w, f.w, acc[1][j]))));
      }
    }
  }
  float add0 = mode ? c1[hh] : 0.f;
  float add1 = mode ? c1[hh + 16] : 0.f;
  float* ob = out + ((size_t)b * NKV + m0) * Hh;
#pragma unroll
  for (int j = 0; j < 4; ++j) {
    ob[(rr + j * 16) * Hh + hh] = acc[0][j] + add0;
    ob[(rr + j * 16) * Hh + hh + 16] = acc[1][j] + add1;
  }
}

// ------------- kernel 2: per-slice sorted top-16 DISTANCES only (branch-free) -------------
__global__ __launch_bounds__(256) void k_selA(
    const char* __restrict__ ws_c, float* __restrict__ pd) {
  __shared__ float4 lk[SL];  // 8 KB slice of packed kv xyz
  int t = threadIdx.x;
  int qt = blockIdx.x, s = blockIdx.y, b = blockIdx.z;
  const float4* kvp = (const float4*)(ws_c + OFF_KVP);
  const float4* qp = (const float4*)(ws_c + OFF_QP);
  const float4* src = kvp + (size_t)b * NKV + s * SL;
#pragma unroll
  for (int i = 0; i < SL / 256; ++i) lk[i * 256 + t] = src[i * 256 + t];
  int q = qt * 256 + t;
  float4 qv = qp[(size_t)b * NQ + q];
  float qx2 = -2.0f * qv.x, qy2 = -2.0f * qv.y, qz2 = -2.0f * qv.z;
  __syncthreads();
  float bd[KNN];
#pragma unroll
  for (int j = 0; j < KNN; ++j) bd[j] = 3.4e38f;
#pragma unroll 4
  for (int mm = 0; mm < SL; ++mm) {
    float v = distkey(qx2, qy2, qz2, lk[mm]);
#pragma unroll
    for (int j = 0; j < KNN; ++j) {  // unconditional sorted insert, 2 ops/step
      float lo = fminf(bd[j], v);
      v = fmaxf(bd[j], v);
      bd[j] = lo;
    }
  }
  float* ob = pd + ((size_t)((size_t)b * NQ + q) * NSL + s) * KNN;
#pragma unroll
  for (int j4 = 0; j4 < 4; ++j4)
    *(float4*)(ob + j4 * 4) = make_float4(bd[j4 * 4], bd[j4 * 4 + 1], bd[j4 * 4 + 2], bd[j4 * 4 + 3]);
}

// ------------- kernel 3: merge lists -> threshold, exact rescan + gather + maxpool + x -------------
// block = 256 threads = 32 queries x 8 slices. tq = t&31, sl = t>>5.
#define MGS 129                     // padded row stride (floats) for merge lists
#define PPS 36                      // padded per-thread pool stride (floats), 16B aligned
__global__ __launch_bounds__(256) void k_selB(
    const float* __restrict__ pd, const char* __restrict__ ws_c,
    float* __restrict__ xout) {
  __shared__ __align__(16) float smem[256 * PPS];  // 36 KB, phase-reused
  __shared__ int cbuf[256];
  int t = threadIdx.x;
  int tq = t & 31, sl = t >> 5;
  int b = blockIdx.y;
  int q = blockIdx.x * 32 + tq;

  // ---- phase 1: load own slice list, publish, merge all 8 lists -> t_thr, budgets ----
  const float* myl = pd + ((size_t)((size_t)b * NQ + q) * NSL + sl) * KNN;
  float own[KNN];
#pragma unroll
  for (int j4 = 0; j4 < 4; ++j4) {
    float4 v = *(const float4*)(myl + j4 * 4);
    own[j4 * 4] = v.x; own[j4 * 4 + 1] = v.y; own[j4 * 4 + 2] = v.z; own[j4 * 4 + 3] = v.w;
  }
#pragma unroll
  for (int j = 0; j < KNN; ++j) smem[tq * MGS + sl * KNN + j] = own[j];
  __syncthreads();
  float bd[KNN];
#pragma unroll
  for (int j = 0; j < KNN; ++j) bd[j] = own[j];
  for (int s2 = 0; s2 < NSL; ++s2) {
    if (s2 == sl) continue;
#pragma unroll
    for (int j = 0; j < KNN; ++j) {
      float v = smem[tq * MGS + s2 * KNN + j];
      if (v < bd[KNN - 1]) {
#pragma unroll
        for (int k = 0; k < KNN; ++k) {
          float lo = fminf(bd[k], v);
          v = fmaxf(bd[k], v);
          bd[k] = lo;
        }
      }
    }
  }
  float t_thr = bd[KNN - 1];
  int m = 0, c = 0;
#pragma unroll
  for (int j = 0; j < KNN; ++j) m += (bd[j] < t_thr) ? 1 : 0;
#pragma unroll
  for (int j = 0; j < KNN; ++j) c += (own[j] == t_thr) ? 1 : 0;
  cbuf[tq * 8 + sl] = c;
  __syncthreads();
  int tie_before = 0;
  for (int s2 = 0; s2 < sl; ++s2) tie_before += cbuf[tq * 8 + s2];
  int b_s = (16 - m) - tie_before;       // remaining tie budget for this slice
  if (b_s < 0) b_s = 0;
  __syncthreads();  // mg region dead; smem reused for pooling

  // ---- phase 2: rescan own slice, accept strict + budgeted ties, gather + maxpool ----
  const float4* kvp = (const float4*)(ws_c + OFF_KVP) + (size_t)b * NKV + sl * SL;
  const float4* qp = (const float4*)(ws_c + OFF_QP);
  const float* kvs = (const float*)(ws_c + OFF_KVS) + (size_t)b * NKV * Hh;
  float4 qv = qp[(size_t)b * NQ + q];
  float qx2 = -2.0f * qv.x, qy2 = -2.0f * qv.y, qz2 = -2.0f * qv.z;
  float4 pool[8];
#pragma unroll
  for (int j = 0; j < 8; ++j) pool[j] = make_float4(-3.4e38f, -3.4e38f, -3.4e38f, -3.4e38f);
  int seen = 0;
#pragma unroll 4
  for (int mm = 0; mm < SL; ++mm) {
    float4 kv = kvp[mm];
    float s0 = distkey(qx2, qy2, qz2, kv);
    if (s0 <= t_thr) {
      bool acc;
      if (s0 < t_thr) acc = true;
      else { acc = (seen < b_s); seen++; }
      if (acc) {
        const float4* row = (const float4*)(kvs + (size_t)(sl * SL + mm) * Hh);
#pragma unroll
        for (int j = 0; j < 8; ++j) {
          float4 vv = row[j];
          pool[j].x = fmaxf(pool[j].x, vv.x); pool[j].y = fmaxf(pool[j].y, vv.y);
          pool[j].z = fmaxf(pool[j].z, vv.z); pool[j].w = fmaxf(pool[j].w, vv.w);
        }
      }
    }
  }

  // ---- phase 3: cross-slice max combine in LDS, + qadd + leaky -> x ----
#pragma unroll
  for (int j = 0; j < 8; ++j) *(float4*)&smem[t * PPS + j * 4] = pool[j];
  __syncthreads();
  if (t < 128) {
#pragma unroll
    for (int j = 0; j < 8; ++j) {
      float4 a = *(float4*)&smem[t * PPS + j * 4];
      float4 bq = *(float4*)&smem[(t + 128) * PPS + j * 4];
      a.x = fmaxf(a.x, bq.x); a.y = fmaxf(a.y, bq.y);
      a.z = fmaxf(a.z, bq.z); a.w = fmaxf(a.w, bq.w);
      *(float4*)&smem[t * PPS + j * 4] = a;
    }
  }
  __syncthreads();
  if (t < 64) {
#pragma unroll
    for (int j = 0; j < 8; ++j) {
      float4 a = *(float4*)&smem[t * PPS + j * 4];
      float4 bq = *(float4*)&smem[(t + 64) * PPS + j * 4];
      a.x = fmaxf(a.x, bq.x); a.y = fmaxf(a.y, bq.y);
      a.z = fmaxf(a.z, bq.z); a.w = fmaxf(a.w, bq.w);
      *(float4*)&smem[t * PPS + j * 4] = a;
    }
  }
  __syncthreads();
  if (t < 32) {
    const float* qadd = (const float*)(ws_c + OFF_QADD);
    int qq = blockIdx.x * 32 + t;
    const float4* qa = (const float4*)(qadd + ((size_t)b * NQ + qq) * Hh);
    float4* xo = (float4*)(xout + ((size_t)b * NQ + qq) * Hh);
#pragma unroll
    for (int j = 0; j < 8; ++j) {
      float4 a = *(float4*)&smem[t * PPS + j * 4];
      float4 bq = *(float4*)&smem[(t + 32) * PPS + j * 4];
      float4 ad = qa[j];
      float4 r;
      r.x = leaky(fmaxf(a.x, bq.x) + ad.x);
      r.y = leaky(fmaxf(a.y, bq.y) + ad.y);
      r.z = leaky(fmaxf(a.z, bq.z) + ad.z);
      r.w = leaky(fmaxf(a.w, bq.w) + ad.w);
      xo[j] = r;
    }
  }
}

// ------------- kernel 4: y = leaky(w2t · x + b2f) -------------
__global__ __launch_bounds__(256) void k_out(
    const float* __restrict__ x, const char* __restrict__ ws_c,
    float* __restrict__ out) {
  int t = threadIdx.x;
  int ql = t & 63, cb = t >> 6;  // cb is wave-uniform -> w2t loads become scalar
  int b = blockIdx.y, q = blockIdx.x * 64 + ql;
  const float* w2t = (const float*)(ws_c + OFF_W2T);
  const float* b2f = (const float*)(ws_c + OFF_B2F);
  const float4* xr = (const float4*)(x + ((size_t)b * NQ + q) * Hh);
  float xv[Hh];
#pragma unroll
  for (int j = 0; j < 8; ++j) {
    float4 v = xr[j];
    xv[4 * j] = v.x; xv[4 * j + 1] = v.y; xv[4 * j + 2] = v.z; xv[4 * j + 3] = v.w;
  }
  float4 acc[16];
#pragma unroll
  for (int c4 = 0; c4 < 16; ++c4) acc[c4] = make_float4(0.f, 0.f, 0.f, 0.f);
#pragma unroll
  for (int h = 0; h < Hh; ++h) {
    float xh = xv[h];
    const float4* wrow = (const float4*)(w2t + (size_t)h * Cc + cb * 64);
#pragma unroll
    for (int c4 = 0; c4 < 16; ++c4) {
      float4 w = wrow[c4];
      acc[c4].x = fmaf(xh, w.x, acc[c4].x);
      acc[c4].y = fmaf(xh, w.y, acc[c4].y);
      acc[c4].z = fmaf(xh, w.z, acc[c4].z);
      acc[c4].w = fmaf(xh, w.w, acc[c4].w);
    }
  }
  float* o = out + ((size_t)b * NQ + q) * Cc + cb * 64;
  const float4* bb = (const float4*)(b2f + cb * 64);
#pragma unroll
  for (int c4 = 0; c4 < 16; ++c4) {
    float4 bv = bb[c4];
    float4 r;
    r.x = leaky(acc[c4].x + bv.x); r.y = leaky(acc[c4].y + bv.y);
    r.z = leaky(acc[c4].z + bv.z); r.w = leaky(acc[c4].w + bv.w);
    *(float4*)(o + c4 * 4) = r;
  }
}

extern "C" void kernel_launch(void* const* d_in, const int* in_sizes, int n_in,
                              void* d_out, int out_size, void* d_ws, size_t ws_size,
                              hipStream_t stream) {
  const float* qf   = (const float*)d_in[0];
  const float* qxyz = (const float*)d_in[1];
  const float* kvf  = (const float*)d_in[2];
  const float* kxyz = (const float*)d_in[3];
  const float* w1 = (const float*)d_in[4];
  const float* g1 = (const float*)d_in[5];
  const float* b1 = (const float*)d_in[6];
  const float* m1 = (const float*)d_in[7];
  const float* v1 = (const float*)d_in[8];
  const float* w2 = (const float*)d_in[9];
  const float* g2 = (const float*)d_in[10];
  const float* b2 = (const float*)d_in[11];
  const float* m2 = (const float*)d_in[12];
  const float* v2 = (const float*)d_in[13];
  char* ws = (char*)d_ws;
  float* pd = (float*)(ws + OFF_PD);
  float* xbuf = (float*)(ws + OFF_X);

  k_prep<<<65, 256, 0, stream>>>(qxyz, kxyz, w1, g1, b1, m1, v1, w2, g2, b2, m2, v2, ws);
  k_selA<<<dim3(NQ / 256, NSL, Bz), 256, 0, stream>>>(ws, pd);
  k_feat<<<dim3(64, Bz, 2), 256, 0, stream>>>(kvf, qf, ws, ws);
  k_selB<<<dim3(NQ / 32, Bz), 256, 0, stream>>>(pd, ws, xbuf);
  k_out<<<dim3(NQ / 64, Bz), 256, 0, stream>>>(xbuf, ws, (float*)d_out);
}

// Round 3
// 394.849 us; speedup vs baseline: 1.5609x; 1.4917x over previous
//
#include <hip/hip_runtime.h>
#include <math.h>

#define Bz 8
#define NQ 4096
#define NKV 4096
#define Cc 256
#define KNN 16
#define Hh 32
#define EPSf 1e-5f
#define SLOPEf 0.2f
#define NSL 4
#define SL 1024 /* NKV / NSL */

typedef unsigned long long u64t;
typedef unsigned int u32t;

// ---- workspace layout (bytes) ----
#define OFF_W1AS 0u                       // 32*256 f32 (alpha1-folded w1a)
#define OFF_W1DS (OFF_W1AS + 32768u)      // 32*256 f32 (alpha1-folded (w1b-w1a))
#define OFF_W2T  (OFF_W1DS + 32768u)      // 32*256 f32 w2t[h][c] = alpha2[c]*w2[c][h]
#define OFF_C1   (OFF_W2T + 32768u)       // 32 f32: b1 - alpha1*m1
#define OFF_B2F  (OFF_C1 + 1024u)         // 256 f32: b2 - alpha2*m2
#define OFF_KVP  (OFF_B2F + 2048u)        // 8*4096 float4 kv xyz (w = |k|^2)
#define OFF_QP   (OFF_KVP + 524288u)      // 8*4096 float4 q xyz (w = |q|^2 + 1)
#define OFF_KVS  (OFF_QP + 524288u)       // 8*4096*32 f32
#define OFF_QADD (OFF_KVS + 4194304u)     // 8*4096*32 f32
#define OFF_PD   (OFF_QADD + 4194304u)    // 8*4096*4*16 u64 per-slice sorted keys (16 MB)
#define OFF_X    OFF_PD                   // 8*4096*32 f32 pooled hidden (aliases dead pd)
#define OFF_IDX  (OFF_PD + 16777216u)     // 8*4096*16 u32 final knn indices (2 MB)
// end = 28,412,928 B (< round-2's 30.5 MB usage)

__device__ __forceinline__ float leaky(float x) { return fmaxf(x, SLOPEf * x); }

// branch-free compare-and-swap on u64 keys (cmp_lt_u64 + 4 cndmask)
#define CAS(A, B) { bool c_ = (A) < (B); u64t lo_ = c_ ? (A) : (B); u64t hi_ = c_ ? (B) : (A); (A) = lo_; (B) = hi_; }
#define MN2(A, B) { (A) = ((B) < (A)) ? (B) : (A); }

// Batcher odd-even mergesort, 16 elements, 63 comparators (c0..c15 ascending)
#define SORTC16 \
  CAS(c0,c1) CAS(c2,c3) CAS(c4,c5) CAS(c6,c7) CAS(c8,c9) CAS(c10,c11) CAS(c12,c13) CAS(c14,c15) \
  CAS(c0,c2) CAS(c4,c6) CAS(c8,c10) CAS(c12,c14) CAS(c1,c3) CAS(c5,c7) CAS(c9,c11) CAS(c13,c15) \
  CAS(c1,c2) CAS(c5,c6) CAS(c9,c10) CAS(c13,c14) \
  CAS(c0,c4) CAS(c8,c12) CAS(c1,c5) CAS(c9,c13) CAS(c2,c6) CAS(c10,c14) CAS(c3,c7) CAS(c11,c15) \
  CAS(c2,c4) CAS(c10,c12) CAS(c3,c5) CAS(c11,c13) \
  CAS(c1,c2) CAS(c3,c4) CAS(c5,c6) CAS(c9,c10) CAS(c11,c12) CAS(c13,c14) \
  CAS(c0,c8) CAS(c1,c9) CAS(c2,c10) CAS(c3,c11) CAS(c4,c12) CAS(c5,c13) CAS(c6,c14) CAS(c7,c15) \
  CAS(c4,c8) CAS(c5,c9) CAS(c6,c10) CAS(c7,c11) \
  CAS(c2,c4) CAS(c3,c5) CAS(c6,c8) CAS(c7,c9) CAS(c10,c12) CAS(c11,c13) \
  CAS(c1,c2) CAS(c3,c4) CAS(c5,c6) CAS(c7,c8) CAS(c9,c10) CAS(c11,c12) CAS(c13,c14)

// keep-lowest-16 of sorted b0..b15 (asc) U sorted c0..c15 (asc):
// pairwise min vs reversed c -> bitonic, then 4-stage bitonic cleaner (32 CAS)
#define MERGE16 \
  MN2(b0,c15) MN2(b1,c14) MN2(b2,c13) MN2(b3,c12) MN2(b4,c11) MN2(b5,c10) MN2(b6,c9) MN2(b7,c8) \
  MN2(b8,c7) MN2(b9,c6) MN2(b10,c5) MN2(b11,c4) MN2(b12,c3) MN2(b13,c2) MN2(b14,c1) MN2(b15,c0) \
  CAS(b0,b8) CAS(b1,b9) CAS(b2,b10) CAS(b3,b11) CAS(b4,b12) CAS(b5,b13) CAS(b6,b14) CAS(b7,b15) \
  CAS(b0,b4) CAS(b1,b5) CAS(b2,b6) CAS(b3,b7) CAS(b8,b12) CAS(b9,b13) CAS(b10,b14) CAS(b11,b15) \
  CAS(b0,b2) CAS(b1,b3) CAS(b4,b6) CAS(b5,b7) CAS(b8,b10) CAS(b9,b11) CAS(b12,b14) CAS(b13,b15) \
  CAS(b0,b1) CAS(b2,b3) CAS(b4,b5) CAS(b6,b7) CAS(b8,b9) CAS(b10,b11) CAS(b12,b13) CAS(b14,b15)

// ---------------- kernel 0: fold weights + pack xyz as float4 ----------------
__global__ __launch_bounds__(256) void k_prep(
    const float* __restrict__ qxyz, const float* __restrict__ kxyz,
    const float* __restrict__ w1, const float* __restrict__ g1,
    const float* __restrict__ b1, const float* __restrict__ m1,
    const float* __restrict__ v1, const float* __restrict__ w2,
    const float* __restrict__ g2, const float* __restrict__ b2,
    const float* __restrict__ m2, const float* __restrict__ v2,
    char* __restrict__ ws) {
  int t = threadIdx.x;
  if (blockIdx.x == 0) {
    __shared__ float a1[Hh], a2c[Cc];
    if (t < Hh) a1[t] = g1[t] / sqrtf(v1[t] + EPSf);
    if (t < Cc) a2c[t] = g2[t] / sqrtf(v2[t] + EPSf);
    __syncthreads();
    float* w1as = (float*)(ws + OFF_W1AS);
    float* w1ds = (float*)(ws + OFF_W1DS);
    float* w2t  = (float*)(ws + OFF_W2T);
    float* c1   = (float*)(ws + OFF_C1);
    float* b2f  = (float*)(ws + OFF_B2F);
    for (int i = t; i < Hh * Cc; i += 256) {
      int h = i >> 8, c = i & 255;
      float wa = w1[h * 2 * Cc + c];
      float wb = w1[h * 2 * Cc + Cc + c];
      w1as[i] = a1[h] * wa;
      w1ds[i] = a1[h] * (wb - wa);
      w2t[i] = a2c[c] * w2[c * Hh + h];   // i = h*256 + c
    }
    if (t < Hh) c1[t] = b1[t] - a1[t] * m1[t];
    if (t < Cc) b2f[t] = b2[t] - a2c[t] * m2[t];
  } else {
    // pack xyz -> float4; kv.w = |k|^2, q.w = |q|^2 + 1 (positivity bias for key order)
    float4* kvp = (float4*)(ws + OFF_KVP);
    float4* qp  = (float4*)(ws + OFF_QP);
    for (int i = 0; i < 4; ++i) {
      int g = (blockIdx.x - 1) * 1024 + i * 256 + t;  // 0..65535
      if (g < Bz * NKV) {
        const float* src = kxyz + (size_t)g * 3;
        float4 v; v.x = src[0]; v.y = src[1]; v.z = src[2];
        v.w = fmaf(v.x, v.x, fmaf(v.y, v.y, v.z * v.z));
        kvp[g] = v;
      } else {
        int g2i = g - Bz * NKV;
        const float* src = qxyz + (size_t)g2i * 3;
        float4 v; v.x = src[0]; v.y = src[1]; v.z = src[2];
        v.w = fmaf(v.x, v.x, fmaf(v.y, v.y, v.z * v.z)) + 1.0f;
        qp[g2i] = v;
      }
    }
  }
}

// ------------- kernel 1: kvs = (a1*w1a)·kv_feat ; qadd = (a1*w1d)·q_feat + c1 -------------
__global__ __launch_bounds__(256) void k_feat(
    const float* __restrict__ kvf, const float* __restrict__ qf,
    const char* __restrict__ ws_c, char* __restrict__ ws_o) {
  __shared__ __align__(16) float fs[64][68];
  __shared__ __align__(16) float wsh[32][68];
  int t = threadIdx.x;
  int hh = t & 15, rr = t >> 4;
  int b = blockIdx.y, m0 = blockIdx.x * 64, mode = blockIdx.z;
  const float* in = mode ? qf : kvf;
  const float* w = (const float*)(ws_c + (mode ? OFF_W1DS : OFF_W1AS));
  const float* c1 = (const float*)(ws_c + OFF_C1);
  float* out = (float*)(ws_o + (mode ? OFF_QADD : OFF_KVS));
  const float* inb = in + ((size_t)b * NKV + m0) * Cc;
  float acc[2][4] = {{0.f, 0.f, 0.f, 0.f}, {0.f, 0.f, 0.f, 0.f}};
  for (int cc = 0; cc < 4; ++cc) {
    __syncthreads();
#pragma unroll
    for (int i = 0; i < 4; ++i) {  // stage 64x64 feat tile
      int l = i * 256 + t, row = l >> 4, c4 = l & 15;
      *(float4*)&fs[row][c4 * 4] = *(const float4*)(inb + (size_t)row * Cc + cc * 64 + c4 * 4);
    }
#pragma unroll
    for (int i = 0; i < 2; ++i) {  // stage 32x64 weight tile
      int l = i * 256 + t, row = l >> 4, c4 = l & 15;
      *(float4*)&wsh[row][c4 * 4] = *(const float4*)(w + (size_t)row * Cc + cc * 64 + c4 * 4);
    }
    __syncthreads();
#pragma unroll
    for (int c4 = 0; c4 < 16; ++c4) {
      float4 w0 = *(float4*)&wsh[hh][c4 * 4];
      float4 w1v = *(float4*)&wsh[hh + 16][c4 * 4];
#pragma unroll
      for (int j = 0; j < 4; ++j) {
        float4 f = *(float4*)&fs[rr + j * 16][c4 * 4];
        acc[0][j] = fmaf(w0.x, f.x, fmaf(w0.y, f.y, fmaf(w0.z, f.z, fmaf(w0.w, f.w, acc[0][j]))));
        acc[1][j] = fmaf(w1v.x, f.x, fmaf(w1v.y, f.y, fmaf(w1v.z, f.z, fmaf(w1v.w, f.w, acc[1][j]))));
      }
    }
  }
  float add0 = mode ? c1[hh] : 0.f;
  float add1 = mode ? c1[hh + 16] : 0.f;
  float* ob = out + ((size_t)b * NKV + m0) * Hh;
#pragma unroll
  for (int j = 0; j < 4; ++j) {
    ob[(rr + j * 16) * Hh + hh] = acc[0][j] + add0;
    ob[(rr + j * 16) * Hh + hh + 16] = acc[1][j] + add1;
  }
}

// ------------- kernel 2: per-slice EXACT top-16 (packed u64 keys, sorting network) -------------
__global__ __launch_bounds__(256) void k_sel(
    const char* __restrict__ ws_c, u64t* __restrict__ pd) {
  __shared__ float4 lk[SL];  // 16 KB slice of packed kv xyz
  int t = threadIdx.x;
  int qt = blockIdx.x, s = blockIdx.y, b = blockIdx.z;
  const float4* kvp = (const float4*)(ws_c + OFF_KVP) + (size_t)b * NKV + s * SL;
  const float4* qp = (const float4*)(ws_c + OFF_QP);
#pragma unroll
  for (int i = 0; i < SL / 256; ++i) lk[i * 256 + t] = kvp[i * 256 + t];
  int q = qt * 256 + t;
  float4 qv = qp[(size_t)b * NQ + q];
  float qx2 = -2.0f * qv.x, qy2 = -2.0f * qv.y, qz2 = -2.0f * qv.z, qw = qv.w;
  __syncthreads();
  // key = {hi: float_bits(|q-k|^2 + 1) , lo: kv index} -> u64 order = (dist, idx) lexicographic
#define KEY(KV, IDX) ((((u64t)__float_as_uint(fmaf(qx2, (KV).x, fmaf(qy2, (KV).y, fmaf(qz2, (KV).z, (KV).w + qw))))) << 32) | (u32t)(IDX))
  u64t b0 = ~0ull, b1 = ~0ull, b2 = ~0ull, b3 = ~0ull, b4 = ~0ull, b5 = ~0ull, b6 = ~0ull, b7 = ~0ull;
  u64t b8 = ~0ull, b9 = ~0ull, b10 = ~0ull, b11 = ~0ull, b12 = ~0ull, b13 = ~0ull, b14 = ~0ull, b15 = ~0ull;
  int gbase = s * SL;
#pragma unroll 1
  for (int blk = 0; blk < SL / 16; ++blk) {
    int o = blk * 16;
    u64t c0 = KEY(lk[o + 0], gbase + o + 0);
    u64t c1 = KEY(lk[o + 1], gbase + o + 1);
    u64t c2 = KEY(lk[o + 2], gbase + o + 2);
    u64t c3 = KEY(lk[o + 3], gbase + o + 3);
    u64t c4 = KEY(lk[o + 4], gbase + o + 4);
    u64t c5 = KEY(lk[o + 5], gbase + o + 5);
    u64t c6 = KEY(lk[o + 6], gbase + o + 6);
    u64t c7 = KEY(lk[o + 7], gbase + o + 7);
    u64t c8 = KEY(lk[o + 8], gbase + o + 8);
    u64t c9 = KEY(lk[o + 9], gbase + o + 9);
    u64t c10 = KEY(lk[o + 10], gbase + o + 10);
    u64t c11 = KEY(lk[o + 11], gbase + o + 11);
    u64t c12 = KEY(lk[o + 12], gbase + o + 12);
    u64t c13 = KEY(lk[o + 13], gbase + o + 13);
    u64t c14 = KEY(lk[o + 14], gbase + o + 14);
    u64t c15 = KEY(lk[o + 15], gbase + o + 15);
    SORTC16
    MERGE16
  }
#undef KEY
  u64t* ob = pd + (((size_t)b * NQ + q) * NSL + s) * KNN;
  ob[0] = b0; ob[1] = b1; ob[2] = b2; ob[3] = b3;
  ob[4] = b4; ob[5] = b5; ob[6] = b6; ob[7] = b7;
  ob[8] = b8; ob[9] = b9; ob[10] = b10; ob[11] = b11;
  ob[12] = b12; ob[13] = b13; ob[14] = b14; ob[15] = b15;
}

// ------------- kernel 3: merge 4 sorted slice lists -> 16 global knn indices -------------
__global__ __launch_bounds__(256) void k_mg(
    const u64t* __restrict__ pd, u32t* __restrict__ idxb) {
  int g = blockIdx.x * 256 + threadIdx.x;  // 0 .. Bz*NQ-1
  const u64t* L = pd + (size_t)g * (NSL * KNN);
  u64t b0 = L[0], b1 = L[1], b2 = L[2], b3 = L[3], b4 = L[4], b5 = L[5], b6 = L[6], b7 = L[7];
  u64t b8 = L[8], b9 = L[9], b10 = L[10], b11 = L[11], b12 = L[12], b13 = L[13], b14 = L[14], b15 = L[15];
#pragma unroll
  for (int s = 1; s < NSL; ++s) {
    const u64t* C = L + s * KNN;
    u64t c0 = C[0], c1 = C[1], c2 = C[2], c3 = C[3], c4 = C[4], c5 = C[5], c6 = C[6], c7 = C[7];
    u64t c8 = C[8], c9 = C[9], c10 = C[10], c11 = C[11], c12 = C[12], c13 = C[13], c14 = C[14], c15 = C[15];
    MERGE16
  }
  u32t* ob = idxb + (size_t)g * KNN;
  ob[0] = (u32t)b0; ob[1] = (u32t)b1; ob[2] = (u32t)b2; ob[3] = (u32t)b3;
  ob[4] = (u32t)b4; ob[5] = (u32t)b5; ob[6] = (u32t)b6; ob[7] = (u32t)b7;
  ob[8] = (u32t)b8; ob[9] = (u32t)b9; ob[10] = (u32t)b10; ob[11] = (u32t)b11;
  ob[12] = (u32t)b12; ob[13] = (u32t)b13; ob[14] = (u32t)b14; ob[15] = (u32t)b15;
}

// ------------- kernel 4: gather kvs rows, maxpool, + qadd, leaky -> x -------------
// 256 threads = 32 queries x 8 lanes; lane j handles float4 j of the 32-dim row (coalesced)
__global__ __launch_bounds__(256) void k_gather(
    const u32t* __restrict__ idxb, const char* __restrict__ ws_c,
    float* __restrict__ xout) {
  int t = threadIdx.x;
  int tq = t >> 3, j = t & 7;
  int b = blockIdx.y, q = blockIdx.x * 32 + tq;
  const u32t* ib = idxb + ((size_t)b * NQ + q) * KNN;
  const float4* kvs = (const float4*)(ws_c + OFF_KVS) + (size_t)b * NKV * 8;
  float4 p = make_float4(-3.4e38f, -3.4e38f, -3.4e38f, -3.4e38f);
#pragma unroll
  for (int n = 0; n < KNN; ++n) {
    u32t m = ib[n];
    float4 v = kvs[(size_t)m * 8 + j];
    p.x = fmaxf(p.x, v.x); p.y = fmaxf(p.y, v.y);
    p.z = fmaxf(p.z, v.z); p.w = fmaxf(p.w, v.w);
  }
  const float4* qa = (const float4*)(ws_c + OFF_QADD) + ((size_t)b * NQ + q) * 8 + j;
  float4 a = *qa;
  float4 r;
  r.x = leaky(p.x + a.x); r.y = leaky(p.y + a.y);
  r.z = leaky(p.z + a.z); r.w = leaky(p.w + a.w);
  ((float4*)xout)[((size_t)b * NQ + q) * 8 + j] = r;
}

// ------------- kernel 5: y = leaky(w2t · x + b2f) -------------
__global__ __launch_bounds__(256) void k_out(
    const float* __restrict__ x, const char* __restrict__ ws_c,
    float* __restrict__ out) {
  int t = threadIdx.x;
  int ql = t & 63, cb = t >> 6;  // cb is wave-uniform -> w2t loads become scalar
  int b = blockIdx.y, q = blockIdx.x * 64 + ql;
  const float* w2t = (const float*)(ws_c + OFF_W2T);
  const float* b2f = (const float*)(ws_c + OFF_B2F);
  const float4* xr = (const float4*)(x + ((size_t)b * NQ + q) * Hh);
  float xv[Hh];
#pragma unroll
  for (int j = 0; j < 8; ++j) {
    float4 v = xr[j];
    xv[4 * j] = v.x; xv[4 * j + 1] = v.y; xv[4 * j + 2] = v.z; xv[4 * j + 3] = v.w;
  }
  float4 acc[16];
#pragma unroll
  for (int c4 = 0; c4 < 16; ++c4) acc[c4] = make_float4(0.f, 0.f, 0.f, 0.f);
#pragma unroll
  for (int h = 0; h < Hh; ++h) {
    float xh = xv[h];
    const float4* wrow = (const float4*)(w2t + (size_t)h * Cc + cb * 64);
#pragma unroll
    for (int c4 = 0; c4 < 16; ++c4) {
      float4 w = wrow[c4];
      acc[c4].x = fmaf(xh, w.x, acc[c4].x);
      acc[c4].y = fmaf(xh, w.y, acc[c4].y);
      acc[c4].z = fmaf(xh, w.z, acc[c4].z);
      acc[c4].w = fmaf(xh, w.w, acc[c4].w);
    }
  }
  float* o = out + ((size_t)b * NQ + q) * Cc + cb * 64;
  const float4* bb = (const float4*)(b2f + cb * 64);
#pragma unroll
  for (int c4 = 0; c4 < 16; ++c4) {
    float4 bv = bb[c4];
    float4 r;
    r.x = leaky(acc[c4].x + bv.x); r.y = leaky(acc[c4].y + bv.y);
    r.z = leaky(acc[c4].z + bv.z); r.w = leaky(acc[c4].w + bv.w);
    *(float4*)(o + c4 * 4) = r;
  }
}

extern "C" void kernel_launch(void* const* d_in, const int* in_sizes, int n_in,
                              void* d_out, int out_size, void* d_ws, size_t ws_size,
                              hipStream_t stream) {
  const float* qf   = (const float*)d_in[0];
  const float* qxyz = (const float*)d_in[1];
  const float* kvf  = (const float*)d_in[2];
  const float* kxyz = (const float*)d_in[3];
  const float* w1 = (const float*)d_in[4];
  const float* g1 = (const float*)d_in[5];
  const float* b1 = (const float*)d_in[6];
  const float* m1 = (const float*)d_in[7];
  const float* v1 = (const float*)d_in[8];
  const float* w2 = (const float*)d_in[9];
  const float* g2 = (const float*)d_in[10];
  const float* b2 = (const float*)d_in[11];
  const float* m2 = (const float*)d_in[12];
  const float* v2 = (const float*)d_in[13];
  char* ws = (char*)d_ws;
  u64t* pd = (u64t*)(ws + OFF_PD);
  u32t* idxb = (u32t*)(ws + OFF_IDX);
  float* xbuf = (float*)(ws + OFF_X);

  k_prep<<<65, 256, 0, stream>>>(qxyz, kxyz, w1, g1, b1, m1, v1, w2, g2, b2, m2, v2, ws);
  k_sel<<<dim3(NQ / 256, NSL, Bz), 256, 0, stream>>>(ws, pd);
  k_feat<<<dim3(64, Bz, 2), 256, 0, stream>>>(kvf, qf, ws, ws);
  k_mg<<<dim3(Bz * NQ / 256), 256, 0, stream>>>(pd, idxb);
  k_gather<<<dim3(NQ / 32, Bz), 256, 0, stream>>>(idxb, ws, xbuf);
  k_out<<<dim3(NQ / 64, Bz), 256, 0, stream>>>(xbuf, ws, (float*)d_out);
}

// Round 4
// 313.353 us; speedup vs baseline: 1.9668x; 1.2601x over previous
//
#include <hip/hip_runtime.h>
#include <math.h>

#define Bz 8
#define NQ 4096
#define NKV 4096
#define Cc 256
#define KNN 16
#define Hh 32
#define EPSf 1e-5f
#define SLOPEf 0.2f
#define NSL 4
#define SL 1024 /* NKV / NSL */

typedef unsigned long long u64t;
typedef unsigned int u32t;

// ---- workspace layout (bytes) ----
#define OFF_W1AS 0u                       // 32*256 f32 (alpha1-folded w1a)
#define OFF_W1DS (OFF_W1AS + 32768u)      // 32*256 f32 (alpha1-folded (w1b-w1a))
#define OFF_W2T  (OFF_W1DS + 32768u)      // 32*256 f32 w2t[h][c] = alpha2[c]*w2[c][h]
#define OFF_C1   (OFF_W2T + 32768u)       // 32 f32: b1 - alpha1*m1
#define OFF_B2F  (OFF_C1 + 1024u)         // 256 f32: b2 - alpha2*m2
#define OFF_KVP  (OFF_B2F + 2048u)        // 8*4096 float4 kv xyz (w = |k|^2)
#define OFF_QP   (OFF_KVP + 524288u)      // 8*4096 float4 q xyz (w = |q|^2 + 1)
#define OFF_KVS  (OFF_QP + 524288u)       // 8*4096*32 f32
#define OFF_QADD (OFF_KVS + 4194304u)     // 8*4096*32 f32
#define OFF_PD   (OFF_QADD + 4194304u)    // 8*4096*4*16 f64 per-slice sorted keys (16 MB)
#define OFF_X    OFF_PD                   // 8*4096*32 f32 pooled hidden (aliases dead pd)
#define OFF_IDX  (OFF_PD + 16777216u)     // 8*4096*16 u32 final knn indices (2 MB)

__device__ __forceinline__ float leaky(float x) { return fmaxf(x, SLOPEf * x); }

// f64 comparators: CAS = v_min_f64 + v_max_f64 (2 instrs); MN2 = v_min_f64 (1)
#define CASD(A, B) { double lo_ = fmin(A, B); double hi_ = fmax(A, B); (A) = lo_; (B) = hi_; }
#define MND(A, B)  { (A) = fmin(A, B); }

// Batcher odd-even mergesort, 16 elements, 63 comparators (c0..c15 ascending)
#define SORTC16 \
  CASD(c0,c1) CASD(c2,c3) CASD(c4,c5) CASD(c6,c7) CASD(c8,c9) CASD(c10,c11) CASD(c12,c13) CASD(c14,c15) \
  CASD(c0,c2) CASD(c4,c6) CASD(c8,c10) CASD(c12,c14) CASD(c1,c3) CASD(c5,c7) CASD(c9,c11) CASD(c13,c15) \
  CASD(c1,c2) CASD(c5,c6) CASD(c9,c10) CASD(c13,c14) \
  CASD(c0,c4) CASD(c8,c12) CASD(c1,c5) CASD(c9,c13) CASD(c2,c6) CASD(c10,c14) CASD(c3,c7) CASD(c11,c15) \
  CASD(c2,c4) CASD(c10,c12) CASD(c3,c5) CASD(c11,c13) \
  CASD(c1,c2) CASD(c3,c4) CASD(c5,c6) CASD(c9,c10) CASD(c11,c12) CASD(c13,c14) \
  CASD(c0,c8) CASD(c1,c9) CASD(c2,c10) CASD(c3,c11) CASD(c4,c12) CASD(c5,c13) CASD(c6,c14) CASD(c7,c15) \
  CASD(c4,c8) CASD(c5,c9) CASD(c6,c10) CASD(c7,c11) \
  CASD(c2,c4) CASD(c3,c5) CASD(c6,c8) CASD(c7,c9) CASD(c10,c12) CASD(c11,c13) \
  CASD(c1,c2) CASD(c3,c4) CASD(c5,c6) CASD(c7,c8) CASD(c9,c10) CASD(c11,c12) CASD(c13,c14)

// keep-lowest-16 of sorted b (asc) U sorted c (asc): reversed pairwise min, bitonic clean
#define MERGE16 \
  MND(b0,c15) MND(b1,c14) MND(b2,c13) MND(b3,c12) MND(b4,c11) MND(b5,c10) MND(b6,c9) MND(b7,c8) \
  MND(b8,c7) MND(b9,c6) MND(b10,c5) MND(b11,c4) MND(b12,c3) MND(b13,c2) MND(b14,c1) MND(b15,c0) \
  CASD(b0,b8) CASD(b1,b9) CASD(b2,b10) CASD(b3,b11) CASD(b4,b12) CASD(b5,b13) CASD(b6,b14) CASD(b7,b15) \
  CASD(b0,b4) CASD(b1,b5) CASD(b2,b6) CASD(b3,b7) CASD(b8,b12) CASD(b9,b13) CASD(b10,b14) CASD(b11,b15) \
  CASD(b0,b2) CASD(b1,b3) CASD(b4,b6) CASD(b5,b7) CASD(b8,b10) CASD(b9,b11) CASD(b12,b14) CASD(b13,b15) \
  CASD(b0,b1) CASD(b2,b3) CASD(b4,b5) CASD(b6,b7) CASD(b8,b9) CASD(b10,b11) CASD(b12,b13) CASD(b14,b15)

// ---------------- kernel 0: fold weights + pack xyz as float4 ----------------
__global__ __launch_bounds__(256) void k_prep(
    const float* __restrict__ qxyz, const float* __restrict__ kxyz,
    const float* __restrict__ w1, const float* __restrict__ g1,
    const float* __restrict__ b1, const float* __restrict__ m1,
    const float* __restrict__ v1, const float* __restrict__ w2,
    const float* __restrict__ g2, const float* __restrict__ b2,
    const float* __restrict__ m2, const float* __restrict__ v2,
    char* __restrict__ ws) {
  int t = threadIdx.x;
  if (blockIdx.x == 0) {
    __shared__ float a1[Hh], a2c[Cc];
    if (t < Hh) a1[t] = g1[t] / sqrtf(v1[t] + EPSf);
    if (t < Cc) a2c[t] = g2[t] / sqrtf(v2[t] + EPSf);
    __syncthreads();
    float* w1as = (float*)(ws + OFF_W1AS);
    float* w1ds = (float*)(ws + OFF_W1DS);
    float* w2t  = (float*)(ws + OFF_W2T);
    float* c1   = (float*)(ws + OFF_C1);
    float* b2f  = (float*)(ws + OFF_B2F);
    for (int i = t; i < Hh * Cc; i += 256) {
      int h = i >> 8, c = i & 255;
      float wa = w1[h * 2 * Cc + c];
      float wb = w1[h * 2 * Cc + Cc + c];
      w1as[i] = a1[h] * wa;
      w1ds[i] = a1[h] * (wb - wa);
      w2t[i] = a2c[c] * w2[c * Hh + h];   // i = h*256 + c
    }
    if (t < Hh) c1[t] = b1[t] - a1[t] * m1[t];
    if (t < Cc) b2f[t] = b2[t] - a2c[t] * m2[t];
  } else {
    // pack xyz -> float4; kv.w = |k|^2, q.w = |q|^2 + 1 (positivity bias for key order)
    float4* kvp = (float4*)(ws + OFF_KVP);
    float4* qp  = (float4*)(ws + OFF_QP);
    for (int i = 0; i < 4; ++i) {
      int g = (blockIdx.x - 1) * 1024 + i * 256 + t;  // 0..65535
      if (g < Bz * NKV) {
        const float* src = kxyz + (size_t)g * 3;
        float4 v; v.x = src[0]; v.y = src[1]; v.z = src[2];
        v.w = fmaf(v.x, v.x, fmaf(v.y, v.y, v.z * v.z));
        kvp[g] = v;
      } else {
        int g2i = g - Bz * NKV;
        const float* src = qxyz + (size_t)g2i * 3;
        float4 v; v.x = src[0]; v.y = src[1]; v.z = src[2];
        v.w = fmaf(v.x, v.x, fmaf(v.y, v.y, v.z * v.z)) + 1.0f;
        qp[g2i] = v;
      }
    }
  }
}

// ------------- kernel 1: kvs = (a1*w1a)·kv_feat ; qadd = (a1*w1d)·q_feat + c1 -------------
__global__ __launch_bounds__(256) void k_feat(
    const float* __restrict__ kvf, const float* __restrict__ qf,
    const char* __restrict__ ws_c, char* __restrict__ ws_o) {
  __shared__ __align__(16) float fs[64][68];
  __shared__ __align__(16) float wsh[32][68];
  int t = threadIdx.x;
  int hh = t & 15, rr = t >> 4;
  int b = blockIdx.y, m0 = blockIdx.x * 64, mode = blockIdx.z;
  const float* in = mode ? qf : kvf;
  const float* w = (const float*)(ws_c + (mode ? OFF_W1DS : OFF_W1AS));
  const float* c1 = (const float*)(ws_c + OFF_C1);
  float* out = (float*)(ws_o + (mode ? OFF_QADD : OFF_KVS));
  const float* inb = in + ((size_t)b * NKV + m0) * Cc;
  float acc[2][4] = {{0.f, 0.f, 0.f, 0.f}, {0.f, 0.f, 0.f, 0.f}};
  for (int cc = 0; cc < 4; ++cc) {
    __syncthreads();
#pragma unroll
    for (int i = 0; i < 4; ++i) {  // stage 64x64 feat tile
      int l = i * 256 + t, row = l >> 4, c4 = l & 15;
      *(float4*)&fs[row][c4 * 4] = *(const float4*)(inb + (size_t)row * Cc + cc * 64 + c4 * 4);
    }
#pragma unroll
    for (int i = 0; i < 2; ++i) {  // stage 32x64 weight tile
      int l = i * 256 + t, row = l >> 4, c4 = l & 15;
      *(float4*)&wsh[row][c4 * 4] = *(const float4*)(w + (size_t)row * Cc + cc * 64 + c4 * 4);
    }
    __syncthreads();
#pragma unroll
    for (int c4 = 0; c4 < 16; ++c4) {
      float4 w0 = *(float4*)&wsh[hh][c4 * 4];
      float4 w1v = *(float4*)&wsh[hh + 16][c4 * 4];
#pragma unroll
      for (int j = 0; j < 4; ++j) {
        float4 f = *(float4*)&fs[rr + j * 16][c4 * 4];
        acc[0][j] = fmaf(w0.x, f.x, fmaf(w0.y, f.y, fmaf(w0.z, f.z, fmaf(w0.w, f.w, acc[0][j]))));
        acc[1][j] = fmaf(w1v.x, f.x, fmaf(w1v.y, f.y, fmaf(w1v.z, f.z, fmaf(w1v.w, f.w, acc[1][j]))));
      }
    }
  }
  float add0 = mode ? c1[hh] : 0.f;
  float add1 = mode ? c1[hh + 16] : 0.f;
  float* ob = out + ((size_t)b * NKV + m0) * Hh;
#pragma unroll
  for (int j = 0; j < 4; ++j) {
    ob[(rr + j * 16) * Hh + hh] = acc[0][j] + add0;
    ob[(rr + j * 16) * Hh + hh + 16] = acc[1][j] + add1;
  }
}

// ------------- kernel 2: per-slice EXACT top-16, f64-packed (dist,idx) keys -------------
// key = fma(double(dist_f32), 2^36, idx): exact (dist>=0.5 => gap >= 4096 > idx_max),
// f64 order == (fp32 dist, global idx) lexicographic == jax top_k tie semantics.
__global__ __launch_bounds__(256) void k_sel(
    const char* __restrict__ ws_c, double* __restrict__ pd) {
  __shared__ float4 lk[SL];  // 16 KB slice of packed kv xyz
  int t = threadIdx.x;
  int qt = blockIdx.x, s = blockIdx.y, b = blockIdx.z;
  const float4* kvp = (const float4*)(ws_c + OFF_KVP) + (size_t)b * NKV + s * SL;
  const float4* qp = (const float4*)(ws_c + OFF_QP);
#pragma unroll
  for (int i = 0; i < SL / 256; ++i) lk[i * 256 + t] = kvp[i * 256 + t];
  int q = qt * 256 + t;
  float4 qv = qp[(size_t)b * NQ + q];
  float qx2 = -2.0f * qv.x, qy2 = -2.0f * qv.y, qz2 = -2.0f * qv.z, qw = qv.w;
  __syncthreads();
  const double SCALE = 68719476736.0;  // 2^36
  int gbase = s * SL;
  double b0 = 1e300, b1 = 1e300, b2 = 1e300, b3 = 1e300, b4 = 1e300, b5 = 1e300, b6 = 1e300, b7 = 1e300;
  double b8 = 1e300, b9 = 1e300, b10 = 1e300, b11 = 1e300, b12 = 1e300, b13 = 1e300, b14 = 1e300, b15 = 1e300;
  double id0 = (double)(gbase + 0), id1 = (double)(gbase + 1), id2 = (double)(gbase + 2), id3 = (double)(gbase + 3);
  double id4 = (double)(gbase + 4), id5 = (double)(gbase + 5), id6 = (double)(gbase + 6), id7 = (double)(gbase + 7);
  double id8 = (double)(gbase + 8), id9 = (double)(gbase + 9), id10 = (double)(gbase + 10), id11 = (double)(gbase + 11);
  double id12 = (double)(gbase + 12), id13 = (double)(gbase + 13), id14 = (double)(gbase + 14), id15 = (double)(gbase + 15);
#define MK(J) { float4 kv = lk[o + J]; \
  float dq = fmaf(qx2, kv.x, fmaf(qy2, kv.y, fmaf(qz2, kv.z, kv.w + qw))); \
  c##J = fma((double)dq, SCALE, id##J); id##J += 16.0; }
#pragma unroll 2
  for (int blk = 0; blk < SL / 16; ++blk) {
    int o = blk * 16;
    double c0, c1, c2, c3, c4, c5, c6, c7, c8, c9, c10, c11, c12, c13, c14, c15;
    MK(0) MK(1) MK(2) MK(3) MK(4) MK(5) MK(6) MK(7)
    MK(8) MK(9) MK(10) MK(11) MK(12) MK(13) MK(14) MK(15)
    SORTC16
    MERGE16
  }
#undef MK
  double* ob = pd + (((size_t)b * NQ + q) * NSL + s) * KNN;
  ob[0] = b0; ob[1] = b1; ob[2] = b2; ob[3] = b3;
  ob[4] = b4; ob[5] = b5; ob[6] = b6; ob[7] = b7;
  ob[8] = b8; ob[9] = b9; ob[10] = b10; ob[11] = b11;
  ob[12] = b12; ob[13] = b13; ob[14] = b14; ob[15] = b15;
}

// ------------- kernel 3: merge 4 sorted slice lists -> 16 global knn indices -------------
__global__ __launch_bounds__(256) void k_mg(
    const double* __restrict__ pd, u32t* __restrict__ idxb) {
  int g = blockIdx.x * 256 + threadIdx.x;  // 0 .. Bz*NQ-1
  const double* L = pd + (size_t)g * (NSL * KNN);
  double b0 = L[0], b1 = L[1], b2 = L[2], b3 = L[3], b4 = L[4], b5 = L[5], b6 = L[6], b7 = L[7];
  double b8 = L[8], b9 = L[9], b10 = L[10], b11 = L[11], b12 = L[12], b13 = L[13], b14 = L[14], b15 = L[15];
#pragma unroll
  for (int s = 1; s < NSL; ++s) {
    const double* C = L + s * KNN;
    double c0 = C[0], c1 = C[1], c2 = C[2], c3 = C[3], c4 = C[4], c5 = C[5], c6 = C[6], c7 = C[7];
    double c8 = C[8], c9 = C[9], c10 = C[10], c11 = C[11], c12 = C[12], c13 = C[13], c14 = C[14], c15 = C[15];
    MERGE16
  }
  // keys are integral (< 2^45); low 12 bits = global-in-batch kv index
  u32t* ob = idxb + (size_t)g * KNN;
  ob[0] = (u32t)((u64t)b0 & 4095u); ob[1] = (u32t)((u64t)b1 & 4095u);
  ob[2] = (u32t)((u64t)b2 & 4095u); ob[3] = (u32t)((u64t)b3 & 4095u);
  ob[4] = (u32t)((u64t)b4 & 4095u); ob[5] = (u32t)((u64t)b5 & 4095u);
  ob[6] = (u32t)((u64t)b6 & 4095u); ob[7] = (u32t)((u64t)b7 & 4095u);
  ob[8] = (u32t)((u64t)b8 & 4095u); ob[9] = (u32t)((u64t)b9 & 4095u);
  ob[10] = (u32t)((u64t)b10 & 4095u); ob[11] = (u32t)((u64t)b11 & 4095u);
  ob[12] = (u32t)((u64t)b12 & 4095u); ob[13] = (u32t)((u64t)b13 & 4095u);
  ob[14] = (u32t)((u64t)b14 & 4095u); ob[15] = (u32t)((u64t)b15 & 4095u);
}

// ------------- kernel 4: gather kvs rows, maxpool, + qadd, leaky -> x -------------
// 256 threads = 32 queries x 8 lanes; lane j handles float4 j of the 32-dim row (coalesced)
__global__ __launch_bounds__(256) void k_gather(
    const u32t* __restrict__ idxb, const char* __restrict__ ws_c,
    float* __restrict__ xout) {
  int t = threadIdx.x;
  int tq = t >> 3, j = t & 7;
  int b = blockIdx.y, q = blockIdx.x * 32 + tq;
  const u32t* ib = idxb + ((size_t)b * NQ + q) * KNN;
  const float4* kvs = (const float4*)(ws_c + OFF_KVS) + (size_t)b * NKV * 8;
  float4 p = make_float4(-3.4e38f, -3.4e38f, -3.4e38f, -3.4e38f);
#pragma unroll
  for (int n = 0; n < KNN; ++n) {
    u32t m = ib[n];
    float4 v = kvs[(size_t)m * 8 + j];
    p.x = fmaxf(p.x, v.x); p.y = fmaxf(p.y, v.y);
    p.z = fmaxf(p.z, v.z); p.w = fmaxf(p.w, v.w);
  }
  const float4* qa = (const float4*)(ws_c + OFF_QADD) + ((size_t)b * NQ + q) * 8 + j;
  float4 a = *qa;
  float4 r;
  r.x = leaky(p.x + a.x); r.y = leaky(p.y + a.y);
  r.z = leaky(p.z + a.z); r.w = leaky(p.w + a.w);
  ((float4*)xout)[((size_t)b * NQ + q) * 8 + j] = r;
}

// ------------- kernel 5: y = leaky(w2t · x + b2f) -------------
__global__ __launch_bounds__(256) void k_out(
    const float* __restrict__ x, const char* __restrict__ ws_c,
    float* __restrict__ out) {
  int t = threadIdx.x;
  int ql = t & 63, cb = t >> 6;  // cb is wave-uniform -> w2t loads become scalar
  int b = blockIdx.y, q = blockIdx.x * 64 + ql;
  const float* w2t = (const float*)(ws_c + OFF_W2T);
  const float* b2f = (const float*)(ws_c + OFF_B2F);
  const float4* xr = (const float4*)(x + ((size_t)b * NQ + q) * Hh);
  float xv[Hh];
#pragma unroll
  for (int j = 0; j < 8; ++j) {
    float4 v = xr[j];
    xv[4 * j] = v.x; xv[4 * j + 1] = v.y; xv[4 * j + 2] = v.z; xv[4 * j + 3] = v.w;
  }
  float4 acc[16];
#pragma unroll
  for (int c4 = 0; c4 < 16; ++c4) acc[c4] = make_float4(0.f, 0.f, 0.f, 0.f);
#pragma unroll
  for (int h = 0; h < Hh; ++h) {
    float xh = xv[h];
    const float4* wrow = (const float4*)(w2t + (size_t)h * Cc + cb * 64);
#pragma unroll
    for (int c4 = 0; c4 < 16; ++c4) {
      float4 w = wrow[c4];
      acc[c4].x = fmaf(xh, w.x, acc[c4].x);
      acc[c4].y = fmaf(xh, w.y, acc[c4].y);
      acc[c4].z = fmaf(xh, w.z, acc[c4].z);
      acc[c4].w = fmaf(xh, w.w, acc[c4].w);
    }
  }
  float* o = out + ((size_t)b * NQ + q) * Cc + cb * 64;
  const float4* bb = (const float4*)(b2f + cb * 64);
#pragma unroll
  for (int c4 = 0; c4 < 16; ++c4) {
    float4 bv = bb[c4];
    float4 r;
    r.x = leaky(acc[c4].x + bv.x); r.y = leaky(acc[c4].y + bv.y);
    r.z = leaky(acc[c4].z + bv.z); r.w = leaky(acc[c4].w + bv.w);
    *(float4*)(o + c4 * 4) = r;
  }
}

extern "C" void kernel_launch(void* const* d_in, const int* in_sizes, int n_in,
                              void* d_out, int out_size, void* d_ws, size_t ws_size,
                              hipStream_t stream) {
  const float* qf   = (const float*)d_in[0];
  const float* qxyz = (const float*)d_in[1];
  const float* kvf  = (const float*)d_in[2];
  const float* kxyz = (const float*)d_in[3];
  const float* w1 = (const float*)d_in[4];
  const float* g1 = (const float*)d_in[5];
  const float* b1 = (const float*)d_in[6];
  const float* m1 = (const float*)d_in[7];
  const float* v1 = (const float*)d_in[8];
  const float* w2 = (const float*)d_in[9];
  const float* g2 = (const float*)d_in[10];
  const float* b2 = (const float*)d_in[11];
  const float* m2 = (const float*)d_in[12];
  const float* v2 = (const float*)d_in[13];
  char* ws = (char*)d_ws;
  double* pd = (double*)(ws + OFF_PD);
  u32t* idxb = (u32t*)(ws + OFF_IDX);
  float* xbuf = (float*)(ws + OFF_X);

  k_prep<<<65, 256, 0, stream>>>(qxyz, kxyz, w1, g1, b1, m1, v1, w2, g2, b2, m2, v2, ws);
  k_sel<<<dim3(NQ / 256, NSL, Bz), 256, 0, stream>>>(ws, pd);
  k_feat<<<dim3(64, Bz, 2), 256, 0, stream>>>(kvf, qf, ws, ws);
  k_mg<<<dim3(Bz * NQ / 256), 256, 0, stream>>>(pd, idxb);
  k_gather<<<dim3(NQ / 32, Bz), 256, 0, stream>>>(idxb, ws, xbuf);
  k_out<<<dim3(NQ / 64, Bz), 256, 0, stream>>>(xbuf, ws, (float*)d_out);
}

// Round 5
// 282.370 us; speedup vs baseline: 2.1826x; 1.1097x over previous
//
#include <hip/hip_runtime.h>
#include <math.h>

#define Bz 8
#define NQ 4096
#define NKV 4096
#define Cc 256
#define KNN 16
#define Hh 32
#define EPSf 1e-5f
#define SLOPEf 0.2f

typedef unsigned long long u64t;
typedef unsigned int u32t;

// ---- workspace layout (bytes) ----
#define OFF_W1AS 0u                       // 32*256 f32 (alpha1-folded w1a)
#define OFF_W1DS (OFF_W1AS + 32768u)      // 32*256 f32 (alpha1-folded (w1b-w1a))
#define OFF_W2T  (OFF_W1DS + 32768u)      // 32*256 f32 w2t[h][c] = alpha2[c]*w2[c][h]
#define OFF_C1   (OFF_W2T + 32768u)       // 32 f32: b1 - alpha1*m1
#define OFF_B2F  (OFF_C1 + 1024u)         // 256 f32: b2 - alpha2*m2
#define OFF_KVP  (OFF_B2F + 2048u)        // 8*4096 float4 kv xyz (w = |k|^2)
#define OFF_QP   (OFF_KVP + 524288u)      // 8*4096 float4 q xyz (w = |q|^2 + 1)
#define OFF_KVS  (OFF_QP + 524288u)       // 8*4096*32 f32
#define OFF_QADD (OFF_KVS + 4194304u)     // 8*4096*32 f32
#define OFF_PD   (OFF_QADD + 4194304u)    // 8*4096*NSL*16 f64 per-slice sorted keys

__device__ __forceinline__ float leaky(float x) { return fmaxf(x, SLOPEf * x); }

// f64 comparators: CAS = v_min_f64 + v_max_f64 (2 instrs); MN2 = v_min_f64 (1)
#define CASD(A, B) { double lo_ = fmin(A, B); double hi_ = fmax(A, B); (A) = lo_; (B) = hi_; }
#define MND(A, B)  { (A) = fmin(A, B); }

// Batcher odd-even mergesort, 16 elements, 63 comparators (c0..c15 ascending)
#define SORTC16 \
  CASD(c0,c1) CASD(c2,c3) CASD(c4,c5) CASD(c6,c7) CASD(c8,c9) CASD(c10,c11) CASD(c12,c13) CASD(c14,c15) \
  CASD(c0,c2) CASD(c4,c6) CASD(c8,c10) CASD(c12,c14) CASD(c1,c3) CASD(c5,c7) CASD(c9,c11) CASD(c13,c15) \
  CASD(c1,c2) CASD(c5,c6) CASD(c9,c10) CASD(c13,c14) \
  CASD(c0,c4) CASD(c8,c12) CASD(c1,c5) CASD(c9,c13) CASD(c2,c6) CASD(c10,c14) CASD(c3,c7) CASD(c11,c15) \
  CASD(c2,c4) CASD(c10,c12) CASD(c3,c5) CASD(c11,c13) \
  CASD(c1,c2) CASD(c3,c4) CASD(c5,c6) CASD(c9,c10) CASD(c11,c12) CASD(c13,c14) \
  CASD(c0,c8) CASD(c1,c9) CASD(c2,c10) CASD(c3,c11) CASD(c4,c12) CASD(c5,c13) CASD(c6,c14) CASD(c7,c15) \
  CASD(c4,c8) CASD(c5,c9) CASD(c6,c10) CASD(c7,c11) \
  CASD(c2,c4) CASD(c3,c5) CASD(c6,c8) CASD(c7,c9) CASD(c10,c12) CASD(c11,c13) \
  CASD(c1,c2) CASD(c3,c4) CASD(c5,c6) CASD(c7,c8) CASD(c9,c10) CASD(c11,c12) CASD(c13,c14)

// keep-lowest-16 of sorted b (asc) U sorted c (asc): reversed pairwise min, bitonic clean
#define MERGE16 \
  MND(b0,c15) MND(b1,c14) MND(b2,c13) MND(b3,c12) MND(b4,c11) MND(b5,c10) MND(b6,c9) MND(b7,c8) \
  MND(b8,c7) MND(b9,c6) MND(b10,c5) MND(b11,c4) MND(b12,c3) MND(b13,c2) MND(b14,c1) MND(b15,c0) \
  CASD(b0,b8) CASD(b1,b9) CASD(b2,b10) CASD(b3,b11) CASD(b4,b12) CASD(b5,b13) CASD(b6,b14) CASD(b7,b15) \
  CASD(b0,b4) CASD(b1,b5) CASD(b2,b6) CASD(b3,b7) CASD(b8,b12) CASD(b9,b13) CASD(b10,b14) CASD(b11,b15) \
  CASD(b0,b2) CASD(b1,b3) CASD(b4,b6) CASD(b5,b7) CASD(b8,b10) CASD(b9,b11) CASD(b12,b14) CASD(b13,b15) \
  CASD(b0,b1) CASD(b2,b3) CASD(b4,b5) CASD(b6,b7) CASD(b8,b9) CASD(b10,b11) CASD(b12,b13) CASD(b14,b15)

// ---------------- kernel 0: fold weights + pack xyz as float4 ----------------
__global__ __launch_bounds__(256) void k_prep(
    const float* __restrict__ qxyz, const float* __restrict__ kxyz,
    const float* __restrict__ w1, const float* __restrict__ g1,
    const float* __restrict__ b1, const float* __restrict__ m1,
    const float* __restrict__ v1, const float* __restrict__ w2,
    const float* __restrict__ g2, const float* __restrict__ b2,
    const float* __restrict__ m2, const float* __restrict__ v2,
    char* __restrict__ ws) {
  int t = threadIdx.x;
  if (blockIdx.x == 0) {
    __shared__ float a1[Hh], a2c[Cc];
    if (t < Hh) a1[t] = g1[t] / sqrtf(v1[t] + EPSf);
    if (t < Cc) a2c[t] = g2[t] / sqrtf(v2[t] + EPSf);
    __syncthreads();
    float* w1as = (float*)(ws + OFF_W1AS);
    float* w1ds = (float*)(ws + OFF_W1DS);
    float* w2t  = (float*)(ws + OFF_W2T);
    float* c1   = (float*)(ws + OFF_C1);
    float* b2f  = (float*)(ws + OFF_B2F);
    for (int i = t; i < Hh * Cc; i += 256) {
      int h = i >> 8, c = i & 255;
      float wa = w1[h * 2 * Cc + c];
      float wb = w1[h * 2 * Cc + Cc + c];
      w1as[i] = a1[h] * wa;
      w1ds[i] = a1[h] * (wb - wa);
      w2t[i] = a2c[c] * w2[c * Hh + h];   // i = h*256 + c
    }
    if (t < Hh) c1[t] = b1[t] - a1[t] * m1[t];
    if (t < Cc) b2f[t] = b2[t] - a2c[t] * m2[t];
  } else {
    // pack xyz -> float4; kv.w = |k|^2, q.w = |q|^2 + 1 (positivity bias for key order)
    float4* kvp = (float4*)(ws + OFF_KVP);
    float4* qp  = (float4*)(ws + OFF_QP);
    for (int i = 0; i < 2; ++i) {
      int g = (blockIdx.x - 1) * 512 + i * 256 + t;  // 0..65535
      if (g < Bz * NKV) {
        const float* src = kxyz + (size_t)g * 3;
        float4 v; v.x = src[0]; v.y = src[1]; v.z = src[2];
        v.w = fmaf(v.x, v.x, fmaf(v.y, v.y, v.z * v.z));
        kvp[g] = v;
      } else {
        int g2i = g - Bz * NKV;
        const float* src = qxyz + (size_t)g2i * 3;
        float4 v; v.x = src[0]; v.y = src[1]; v.z = src[2];
        v.w = fmaf(v.x, v.x, fmaf(v.y, v.y, v.z * v.z)) + 1.0f;
        qp[g2i] = v;
      }
    }
  }
}

// ------------- kernel 1: kvs = (a1*w1a)·kv_feat ; qadd = (a1*w1d)·q_feat + c1 -------------
__global__ __launch_bounds__(256) void k_feat(
    const float* __restrict__ kvf, const float* __restrict__ qf,
    const char* __restrict__ ws_c, char* __restrict__ ws_o) {
  __shared__ __align__(16) float fs[64][68];
  __shared__ __align__(16) float wsh[32][68];
  int t = threadIdx.x;
  int hh = t & 15, rr = t >> 4;
  int b = blockIdx.y, m0 = blockIdx.x * 64, mode = blockIdx.z;
  const float* in = mode ? qf : kvf;
  const float* w = (const float*)(ws_c + (mode ? OFF_W1DS : OFF_W1AS));
  const float* c1 = (const float*)(ws_c + OFF_C1);
  float* out = (float*)(ws_o + (mode ? OFF_QADD : OFF_KVS));
  const float* inb = in + ((size_t)b * NKV + m0) * Cc;
  float acc[2][4] = {{0.f, 0.f, 0.f, 0.f}, {0.f, 0.f, 0.f, 0.f}};
  for (int cc = 0; cc < 4; ++cc) {
    __syncthreads();
#pragma unroll
    for (int i = 0; i < 4; ++i) {  // stage 64x64 feat tile
      int l = i * 256 + t, row = l >> 4, c4 = l & 15;
      *(float4*)&fs[row][c4 * 4] = *(const float4*)(inb + (size_t)row * Cc + cc * 64 + c4 * 4);
    }
#pragma unroll
    for (int i = 0; i < 2; ++i) {  // stage 32x64 weight tile
      int l = i * 256 + t, row = l >> 4, c4 = l & 15;
      *(float4*)&wsh[row][c4 * 4] = *(const float4*)(w + (size_t)row * Cc + cc * 64 + c4 * 4);
    }
    __syncthreads();
#pragma unroll
    for (int c4 = 0; c4 < 16; ++c4) {
      float4 w0 = *(float4*)&wsh[hh][c4 * 4];
      float4 w1v = *(float4*)&wsh[hh + 16][c4 * 4];
#pragma unroll
      for (int j = 0; j < 4; ++j) {
        float4 f = *(float4*)&fs[rr + j * 16][c4 * 4];
        acc[0][j] = fmaf(w0.x, f.x, fmaf(w0.y, f.y, fmaf(w0.z, f.z, fmaf(w0.w, f.w, acc[0][j]))));
        acc[1][j] = fmaf(w1v.x, f.x, fmaf(w1v.y, f.y, fmaf(w1v.z, f.z, fmaf(w1v.w, f.w, acc[1][j]))));
      }
    }
  }
  float add0 = mode ? c1[hh] : 0.f;
  float add1 = mode ? c1[hh + 16] : 0.f;
  float* ob = out + ((size_t)b * NKV + m0) * Hh;
#pragma unroll
  for (int j = 0; j < 4; ++j) {
    ob[(rr + j * 16) * Hh + hh] = acc[0][j] + add0;
    ob[(rr + j * 16) * Hh + hh + 16] = acc[1][j] + add1;
  }
}

// ------------- kernel 2: per-slice EXACT top-16, f64-packed (dist,idx) keys -------------
// key = fma(double(dist_f32), 2^36, idx): exact (dist>=0.5 => ulp gap >= 4096 > idx_max),
// f64 order == (fp32 dist, global idx) lexicographic == jax top_k tie semantics.
template <int SLt>
__global__ __launch_bounds__(256) void k_sel(
    const char* __restrict__ ws_c, double* __restrict__ pd) {
  constexpr int NSLt = NKV / SLt;
  __shared__ float4 lk[SLt];
  int t = threadIdx.x;
  int qt = blockIdx.x, s = blockIdx.y, b = blockIdx.z;
  const float4* kvp = (const float4*)(ws_c + OFF_KVP) + (size_t)b * NKV + s * SLt;
  const float4* qp = (const float4*)(ws_c + OFF_QP);
#pragma unroll
  for (int i = 0; i < SLt / 256; ++i) lk[i * 256 + t] = kvp[i * 256 + t];
  int q = qt * 256 + t;
  float4 qv = qp[(size_t)b * NQ + q];
  float qx2 = -2.0f * qv.x, qy2 = -2.0f * qv.y, qz2 = -2.0f * qv.z, qw = qv.w;
  __syncthreads();
  const double SCALE = 68719476736.0;  // 2^36
  int gbase = s * SLt;
  double b0 = 1e300, b1 = 1e300, b2 = 1e300, b3 = 1e300, b4 = 1e300, b5 = 1e300, b6 = 1e300, b7 = 1e300;
  double b8 = 1e300, b9 = 1e300, b10 = 1e300, b11 = 1e300, b12 = 1e300, b13 = 1e300, b14 = 1e300, b15 = 1e300;
  double id0 = (double)(gbase + 0), id1 = (double)(gbase + 1), id2 = (double)(gbase + 2), id3 = (double)(gbase + 3);
  double id4 = (double)(gbase + 4), id5 = (double)(gbase + 5), id6 = (double)(gbase + 6), id7 = (double)(gbase + 7);
  double id8 = (double)(gbase + 8), id9 = (double)(gbase + 9), id10 = (double)(gbase + 10), id11 = (double)(gbase + 11);
  double id12 = (double)(gbase + 12), id13 = (double)(gbase + 13), id14 = (double)(gbase + 14), id15 = (double)(gbase + 15);
#define MK(J) { float4 kv = lk[o + J]; \
  float dq = fmaf(qx2, kv.x, fmaf(qy2, kv.y, fmaf(qz2, kv.z, kv.w + qw))); \
  c##J = fma((double)dq, SCALE, id##J); id##J += 16.0; }
#pragma unroll 2
  for (int blk = 0; blk < SLt / 16; ++blk) {
    int o = blk * 16;
    double c0, c1, c2, c3, c4, c5, c6, c7, c8, c9, c10, c11, c12, c13, c14, c15;
    MK(0) MK(1) MK(2) MK(3) MK(4) MK(5) MK(6) MK(7)
    MK(8) MK(9) MK(10) MK(11) MK(12) MK(13) MK(14) MK(15)
    SORTC16
    MERGE16
  }
#undef MK
  double* ob = pd + (((size_t)b * NQ + q) * NSLt + s) * KNN;
  ob[0] = b0; ob[1] = b1; ob[2] = b2; ob[3] = b3;
  ob[4] = b4; ob[5] = b5; ob[6] = b6; ob[7] = b7;
  ob[8] = b8; ob[9] = b9; ob[10] = b10; ob[11] = b11;
  ob[12] = b12; ob[13] = b13; ob[14] = b14; ob[15] = b15;
}

// ------------- kernel 3 (fused tail): merge lists -> gather+maxpool+leaky -> matvec+BN2+leaky -------------
// block = 256 threads, 64 queries. Phases: (1a) 2 threads/q merge half-lists; (1b) 1 thread/q final
// merge -> sidx; (2) 4 lanes/q gather kvs rows + maxpool + qadd + leaky -> xs (transposed);
// (3) 64 q x 4 cb-waves: y = leaky(w2t·x + b2f).
template <int NSLt>
__global__ __launch_bounds__(256) void k_tail(
    const double* __restrict__ pd, const char* __restrict__ ws_c,
    float* __restrict__ out) {
  __shared__ double mg[64][2][KNN];   // 16 KB
  __shared__ int sidx[64 * 17];       // 4.25 KB (stride-17 pad)
  __shared__ float xs[Hh * 64];       // 8 KB, transposed: xs[h][q]
  int t = threadIdx.x;
  int b = blockIdx.y, q0 = blockIdx.x * 64;

  // ---- phase 1a ----
  if (t < 128) {
    int q = t >> 1, p = t & 1;
    constexpr int half = NSLt / 2;
    const double* L = pd + (((size_t)b * NQ + q0 + q) * NSLt + (size_t)p * half) * KNN;
    double b0 = L[0], b1 = L[1], b2 = L[2], b3 = L[3], b4 = L[4], b5 = L[5], b6 = L[6], b7 = L[7];
    double b8 = L[8], b9 = L[9], b10 = L[10], b11 = L[11], b12 = L[12], b13 = L[13], b14 = L[14], b15 = L[15];
#pragma unroll
    for (int s = 1; s < half; ++s) {
      const double* C = L + (size_t)s * KNN;
      double c0 = C[0], c1 = C[1], c2 = C[2], c3 = C[3], c4 = C[4], c5 = C[5], c6 = C[6], c7 = C[7];
      double c8 = C[8], c9 = C[9], c10 = C[10], c11 = C[11], c12 = C[12], c13 = C[13], c14 = C[14], c15 = C[15];
      MERGE16
    }
    double* m = &mg[q][p][0];
    m[0] = b0; m[1] = b1; m[2] = b2; m[3] = b3; m[4] = b4; m[5] = b5; m[6] = b6; m[7] = b7;
    m[8] = b8; m[9] = b9; m[10] = b10; m[11] = b11; m[12] = b12; m[13] = b13; m[14] = b14; m[15] = b15;
  }
  __syncthreads();
  // ---- phase 1b ----
  if (t < 64) {
    const double* A = &mg[t][0][0];
    const double* C2 = &mg[t][1][0];
    double b0 = A[0], b1 = A[1], b2 = A[2], b3 = A[3], b4 = A[4], b5 = A[5], b6 = A[6], b7 = A[7];
    double b8 = A[8], b9 = A[9], b10 = A[10], b11 = A[11], b12 = A[12], b13 = A[13], b14 = A[14], b15 = A[15];
    double c0 = C2[0], c1 = C2[1], c2 = C2[2], c3 = C2[3], c4 = C2[4], c5 = C2[5], c6 = C2[6], c7 = C2[7];
    double c8 = C2[8], c9 = C2[9], c10 = C2[10], c11 = C2[11], c12 = C2[12], c13 = C2[13], c14 = C2[14], c15 = C2[15];
    MERGE16
    int* si = &sidx[t * 17];
    si[0] = (int)((u64t)b0 & 4095u); si[1] = (int)((u64t)b1 & 4095u);
    si[2] = (int)((u64t)b2 & 4095u); si[3] = (int)((u64t)b3 & 4095u);
    si[4] = (int)((u64t)b4 & 4095u); si[5] = (int)((u64t)b5 & 4095u);
    si[6] = (int)((u64t)b6 & 4095u); si[7] = (int)((u64t)b7 & 4095u);
    si[8] = (int)((u64t)b8 & 4095u); si[9] = (int)((u64t)b9 & 4095u);
    si[10] = (int)((u64t)b10 & 4095u); si[11] = (int)((u64t)b11 & 4095u);
    si[12] = (int)((u64t)b12 & 4095u); si[13] = (int)((u64t)b13 & 4095u);
    si[14] = (int)((u64t)b14 & 4095u); si[15] = (int)((u64t)b15 & 4095u);
  }
  __syncthreads();
  // ---- phase 2: gather + maxpool + qadd + leaky -> xs (transposed) ----
  {
    int q = t >> 2, l = t & 3;
    const float4* kvs = (const float4*)(ws_c + OFF_KVS) + (size_t)b * NKV * 8 + l * 2;
    float4 p0 = make_float4(-3.4e38f, -3.4e38f, -3.4e38f, -3.4e38f);
    float4 p1 = p0;
#pragma unroll
    for (int n = 0; n < KNN; ++n) {
      int m = sidx[q * 17 + n];
      const float4* row = kvs + (size_t)m * 8;
      float4 v0 = row[0], v1 = row[1];
      p0.x = fmaxf(p0.x, v0.x); p0.y = fmaxf(p0.y, v0.y); p0.z = fmaxf(p0.z, v0.z); p0.w = fmaxf(p0.w, v0.w);
      p1.x = fmaxf(p1.x, v1.x); p1.y = fmaxf(p1.y, v1.y); p1.z = fmaxf(p1.z, v1.z); p1.w = fmaxf(p1.w, v1.w);
    }
    const float4* qa = (const float4*)(ws_c + OFF_QADD) + ((size_t)b * NQ + q0 + q) * 8 + l * 2;
    float4 a0 = qa[0], a1 = qa[1];
    int h0 = 8 * l;
    xs[(h0 + 0) * 64 + q] = leaky(p0.x + a0.x);
    xs[(h0 + 1) * 64 + q] = leaky(p0.y + a0.y);
    xs[(h0 + 2) * 64 + q] = leaky(p0.z + a0.z);
    xs[(h0 + 3) * 64 + q] = leaky(p0.w + a0.w);
    xs[(h0 + 4) * 64 + q] = leaky(p1.x + a1.x);
    xs[(h0 + 5) * 64 + q] = leaky(p1.y + a1.y);
    xs[(h0 + 6) * 64 + q] = leaky(p1.z + a1.z);
    xs[(h0 + 7) * 64 + q] = leaky(p1.w + a1.w);
  }
  __syncthreads();
  // ---- phase 3: y = leaky(w2t · x + b2f) ----
  {
    int ql = t & 63, cb = t >> 6;  // cb wave-uniform -> w2t loads become scalar
    const float* w2t = (const float*)(ws_c + OFF_W2T);
    const float* b2f = (const float*)(ws_c + OFF_B2F);
    float xv[Hh];
#pragma unroll
    for (int h = 0; h < Hh; ++h) xv[h] = xs[h * 64 + ql];
    float4 acc[16];
#pragma unroll
    for (int c4 = 0; c4 < 16; ++c4) acc[c4] = make_float4(0.f, 0.f, 0.f, 0.f);
#pragma unroll
    for (int h = 0; h < Hh; ++h) {
      float xh = xv[h];
      const float4* wrow = (const float4*)(w2t + (size_t)h * Cc + cb * 64);
#pragma unroll
      for (int c4 = 0; c4 < 16; ++c4) {
        float4 w = wrow[c4];
        acc[c4].x = fmaf(xh, w.x, acc[c4].x);
        acc[c4].y = fmaf(xh, w.y, acc[c4].y);
        acc[c4].z = fmaf(xh, w.z, acc[c4].z);
        acc[c4].w = fmaf(xh, w.w, acc[c4].w);
      }
    }
    float* o = out + ((size_t)b * NQ + q0 + ql) * Cc + cb * 64;
    const float4* bb = (const float4*)(b2f + cb * 64);
#pragma unroll
    for (int c4 = 0; c4 < 16; ++c4) {
      float4 bv = bb[c4];
      float4 r;
      r.x = leaky(acc[c4].x + bv.x); r.y = leaky(acc[c4].y + bv.y);
      r.z = leaky(acc[c4].z + bv.z); r.w = leaky(acc[c4].w + bv.w);
      *(float4*)(o + c4 * 4) = r;
    }
  }
}

extern "C" void kernel_launch(void* const* d_in, const int* in_sizes, int n_in,
                              void* d_out, int out_size, void* d_ws, size_t ws_size,
                              hipStream_t stream) {
  const float* qf   = (const float*)d_in[0];
  const float* qxyz = (const float*)d_in[1];
  const float* kvf  = (const float*)d_in[2];
  const float* kxyz = (const float*)d_in[3];
  const float* w1 = (const float*)d_in[4];
  const float* g1 = (const float*)d_in[5];
  const float* b1 = (const float*)d_in[6];
  const float* m1 = (const float*)d_in[7];
  const float* v1 = (const float*)d_in[8];
  const float* w2 = (const float*)d_in[9];
  const float* g2 = (const float*)d_in[10];
  const float* b2 = (const float*)d_in[11];
  const float* m2 = (const float*)d_in[12];
  const float* v2 = (const float*)d_in[13];
  char* ws = (char*)d_ws;
  double* pd = (double*)(ws + OFF_PD);

  // NSL=8 needs OFF_PD + 8*4096*8*16*8 = ~42.5 MB of ws; fall back to NSL=4 otherwise.
  size_t need8 = (size_t)OFF_PD + (size_t)Bz * NQ * 8 * KNN * sizeof(double);
  bool big = ws_size >= need8;

  k_prep<<<129, 256, 0, stream>>>(qxyz, kxyz, w1, g1, b1, m1, v1, w2, g2, b2, m2, v2, ws);
  if (big) {
    k_sel<512><<<dim3(NQ / 256, 8, Bz), 256, 0, stream>>>(ws, pd);
  } else {
    k_sel<1024><<<dim3(NQ / 256, 4, Bz), 256, 0, stream>>>(ws, pd);
  }
  k_feat<<<dim3(64, Bz, 2), 256, 0, stream>>>(kvf, qf, ws, ws);
  if (big) {
    k_tail<8><<<dim3(NQ / 64, Bz), 256, 0, stream>>>(pd, ws, (float*)d_out);
  } else {
    k_tail<4><<<dim3(NQ / 64, Bz), 256, 0, stream>>>(pd, ws, (float*)d_out);
  }
}